// Round 5
// baseline (7275.142 us; speedup 1.0000x reference)
//
#include <hip/hip_runtime.h>

#define NNODE 1000
#define NBATCH 8
#define SEQL 12
#define NHEAD 8
#define DHEAD 16
#define HID 128
#define NEDGE 16000
#define NROWS (NBATCH*NNODE)   // 8000
#define RPB 32                 // rows per persistent block
#define NBLK_P (NROWS/RPB)     // 250 blocks <= 256 CUs -> co-resident at 1 block/CU
#define PTHREADS 512
#define ORPB 16
#define NBLK_O (NROWS/ORPB)    // 500
#define DT 0.25f
#define ECAP 768               // LDS edge cache (block mean 512, sd ~23)
#define SPIN_LIMIT 10000ULL    // 100 us @ 100 MHz s_memrealtime — anti-deadlock escape

// ---- grid barrier: monotonic epoch counter, device-scope atomics ----
// Pre-barrier __syncthreads drains ALL block stores to the XCD L2 (compiler
// emits s_waitcnt vmcnt(0) before s_barrier); thread0's __threadfence then
// writes back the whole L2 (release) / invalidates L1+L2 (acquire), which
// covers every thread of the block since a block lives on one CU.
__device__ __forceinline__ void grid_bar(int* bar, int target){
  __syncthreads();
  if (threadIdx.x == 0){
    __threadfence();
    __hip_atomic_fetch_add(bar, 1, __ATOMIC_RELEASE, __HIP_MEMORY_SCOPE_AGENT);
    unsigned long long t0 = __builtin_amdgcn_s_memrealtime();
    while (__hip_atomic_load(bar, __ATOMIC_RELAXED, __HIP_MEMORY_SCOPE_AGENT) < target){
      __builtin_amdgcn_s_sleep(2);
      if (__builtin_amdgcn_s_memrealtime() - t0 > SPIN_LIMIT) break;  // escape hatch
    }
    __threadfence();
  }
  __syncthreads();
}

// copy a 128x128 fp32 matrix global->LDS, NT threads
template<int NT>
__device__ __forceinline__ void load_W(float* Wl, const float* g, int tid){
  #pragma unroll
  for (int c = 0; c < (HID*HID/4)/NT; ++c){
    int e = (c*NT + tid)*4;
    *reinterpret_cast<float4*>(Wl + e) = *reinterpret_cast<const float4*>(g + e);
  }
}

// C[row][j] = sum_k yt[row][k]*Wl[k][j]; thread covers cols fg*4..fg*4+3 for
// rows rs and rs+RSTEP.
template<int RSTEP>
__device__ __forceinline__ void gemm128(const float* Wl, const float* yt, int fg, int rs,
                                        float o0[4], float o1[4]){
  float a0[4]={0.f,0.f,0.f,0.f}, a1[4]={0.f,0.f,0.f,0.f};
  #pragma unroll 4
  for (int k=0;k<HID;k+=4){
    float4 ya = *reinterpret_cast<const float4*>(yt + rs*HID + k);
    float4 yb = *reinterpret_cast<const float4*>(yt + (rs+RSTEP)*HID + k);
    #pragma unroll
    for (int kk=0;kk<4;++kk){
      const float* wr = Wl + (k+kk)*HID + fg*4;
      float av = (&ya.x)[kk];
      float bv = (&yb.x)[kk];
      #pragma unroll
      for (int i=0;i<4;++i){
        float w = wr[i];
        a0[i] = fmaf(w, av, a0[i]);
        a1[i] = fmaf(w, bv, a1[i]);
      }
    }
  }
  #pragma unroll
  for (int i=0;i<4;++i){ o0[i]=a0[i]; o1[i]=a1[i]; }
}

// acc[0..7] += wt * {v0.xyzw, v1.xyzw}
__device__ __forceinline__ void acc8(float acc[8], float wt, const float4& v0, const float4& v1){
  acc[0]=fmaf(wt,v0.x,acc[0]); acc[1]=fmaf(wt,v0.y,acc[1]);
  acc[2]=fmaf(wt,v0.z,acc[2]); acc[3]=fmaf(wt,v0.w,acc[3]);
  acc[4]=fmaf(wt,v1.x,acc[4]); acc[5]=fmaf(wt,v1.y,acc[5]);
  acc[6]=fmaf(wt,v1.z,acc[6]); acc[7]=fmaf(wt,v1.w,acc[7]);
}

// GEMM h = yt @ Wl; h + el to global, own-row er to LDS. rows rs, rs+16.
__device__ __forceinline__ void gemm_epi(const float* Wl, const float* yt,
    int fg, int rs, int row0,
    float* __restrict__ h_wr, float* __restrict__ el_wr, float* er_l,
    const float al4[4], const float ar4[4])
{
  float o0[4], o1[4];
  gemm128<16>(Wl, yt, fg, rs, o0, o1);
  const int rowF0 = row0 + rs, rowF1 = row0 + rs + 16;
  *reinterpret_cast<float4*>(h_wr + rowF0*HID + fg*4) = make_float4(o0[0],o0[1],o0[2],o0[3]);
  *reinterpret_cast<float4*>(h_wr + rowF1*HID + fg*4) = make_float4(o1[0],o1[1],o1[2],o1[3]);
  const int hd2 = fg >> 2;
  float elA=0.f, erA=0.f, elB=0.f, erB=0.f;
  #pragma unroll
  for (int i=0;i<4;++i){
    elA = fmaf(o0[i], al4[i], elA); erA = fmaf(o0[i], ar4[i], erA);
    elB = fmaf(o1[i], al4[i], elB); erB = fmaf(o1[i], ar4[i], erB);
  }
  elA += __shfl_xor(elA,1); elA += __shfl_xor(elA,2);
  erA += __shfl_xor(erA,1); erA += __shfl_xor(erA,2);
  elB += __shfl_xor(elB,1); elB += __shfl_xor(elB,2);
  erB += __shfl_xor(erB,1); erB += __shfl_xor(erB,2);
  if ((fg & 3) == 0){
    el_wr[rowF0*NHEAD + hd2] = elA; er_l[rs*NHEAD + hd2]      = erA;
    el_wr[rowF1*NHEAD + hd2] = elB; er_l[(rs+16)*NHEAD + hd2] = erB;
  }
}

// Build CSR (edges sorted by dst); also zero the grid-barrier counter.
__global__ void csr_kernel(const int* __restrict__ src, const int* __restrict__ dst,
                           int* __restrict__ row_start, int* __restrict__ edge_src,
                           int* __restrict__ bar){
  __shared__ int cnt[1024];
  __shared__ int scanb[1024];
  __shared__ int cur[1024];
  int tid = threadIdx.x;
  if (tid == 0) bar[0] = 0;
  cnt[tid] = 0;
  __syncthreads();
  for (int e = tid; e < NEDGE; e += 1024) atomicAdd(&cnt[dst[e]], 1);
  __syncthreads();
  int v = cnt[tid];
  scanb[tid] = v;
  __syncthreads();
  for (int off=1; off<1024; off<<=1){
    int t = (tid >= off) ? scanb[tid-off] : 0;
    __syncthreads();
    scanb[tid] += t;
    __syncthreads();
  }
  int incl = scanb[tid];
  if (tid < NNODE){ cur[tid] = incl - v; row_start[tid+1] = incl; }
  if (tid == 0) row_start[0] = 0;
  __syncthreads();
  for (int e = tid; e < NEDGE; e += 1024){
    int d = dst[e];
    int pos = atomicAdd(&cur[d], 1);
    edge_src[pos] = src[e];
  }
}

struct PArgs {
  float* hb0; float* elb0; float* hb1; float* elb1; float* y_out;
  const int* row_start; const int* edge_src;
  const float* w_gat; const float* a_l; const float* a_r;
  const float* inputs; const float* w_in; const float* b_in;
  const float* w_W; const float* b_W; const float* w_U; const float* b_U;
  int* bar;
};

__global__ void __launch_bounds__(PTHREADS, 2) persist(PArgs p)
{
  __shared__ float Wl[HID*HID];      // 64 KB — w_gat resident except around GRU
  __shared__ float yt[RPB*HID];      // 16 KB
  __shared__ int   esrc_l[ECAP];     // 3 KB edge cache
  __shared__ int   eoff[RPB+1];
  __shared__ int   degs_s[RPB];
  __shared__ float er_l[RPB*NHEAD];  // 1 KB; total ~86 KB -> exactly 1 block/CU

  const int tid  = threadIdx.x;
  const int row0 = blockIdx.x * RPB;
  // layout A: 16 threads per row (32 rows)
  const int rA = tid >> 4, tA = tid & 15;
  const int rowA = row0 + rA;
  const int bA = rowA / NNODE;
  const int nA = rowA - bA * NNODE;
  const int sbase = bA * NNODE;
  const int hd   = tA >> 1;
  const int off8 = tA * 8;
  // layout F: 32 col-groups x 16 row-slots; rows rs, rs+16
  const int fg = tid & 31, rs = tid >> 5;
  const int rowF0 = row0 + rs, rowF1 = row0 + rs + 16;
  const int hd2 = fg >> 2, db = (fg & 3) * 4;

  // ---- one-time: per-block edge cache ----
  const int s0r  = p.row_start[nA];
  const int degr = p.row_start[nA+1] - s0r;
  if (tA == 0) degs_s[rA] = degr;
  __syncthreads();
  if (tid == 0){
    int o = 0;
    #pragma unroll
    for (int r = 0; r < RPB; ++r){ eoff[r] = o; o += degs_s[r]; }
    eoff[RPB] = o;
  }
  __syncthreads();
  const int* eptr;
  if (eoff[RPB] <= ECAP){
    const int eb = eoff[rA];
    for (int e = tA; e < degr; e += 16) esrc_l[eb + e] = p.edge_src[s0r + e];
    eptr = esrc_l + eb;
  } else {
    eptr = p.edge_src + s0r;   // statistically never; correctness fallback
  }

  // ---- one-time: per-thread constants ----
  float wi0[8], wi1[8], bi8[8];
  #pragma unroll
  for (int i=0;i<8;++i){
    int f = off8 + i;
    wi0[i] = p.w_in[f]; wi1[i] = p.w_in[HID+f]; bi8[i] = p.b_in[f];
  }
  float al4[4], ar4[4], bb4[4];
  #pragma unroll
  for (int i=0;i<4;++i){
    al4[i] = p.a_l[hd2*DHEAD + db + i];
    ar4[i] = p.a_r[hd2*DHEAD + db + i];
    bb4[i] = p.b_W[fg*4+i] + p.b_U[fg*4+i];
  }

  load_W<PTHREADS>(Wl, p.w_gat, tid);

  // ---- init: y0 = inputs[:,0]@w_in + b_in ----
  float yb8[8], ya8[8];
  {
    const float x0 = p.inputs[((bA*SEQL + 0)*NNODE + nA)*2 + 0];
    const float x1 = p.inputs[((bA*SEQL + 0)*NNODE + nA)*2 + 1];
    #pragma unroll
    for (int i=0;i<8;++i) yb8[i] = x0*wi0[i] + x1*wi1[i] + bi8[i];
    *reinterpret_cast<float4*>(yt + rA*HID + off8)     = make_float4(yb8[0],yb8[1],yb8[2],yb8[3]);
    *reinterpret_cast<float4*>(yt + rA*HID + off8 + 4) = make_float4(yb8[4],yb8[5],yb8[6],yb8[7]);
  }
  __syncthreads();     // covers yt, Wl, esrc_l, eoff staging
  gemm_epi(Wl, yt, fg, rs, row0, p.hb0, p.elb0, er_l, al4, ar4);

  int step = 1;
  grid_bar(p.bar, NBLK_P * step); ++step;

  int rd = 0;
  for (int idx = 0; idx < SEQL; ++idx){
    for (int st = 0; st < 4; ++st){
      for (int j = 1; j <= 4; ++j){
        const float* __restrict__ h_rd  = rd ? p.hb1  : p.hb0;
        const float* __restrict__ el_rd = rd ? p.elb1 : p.elb0;
        float* __restrict__ h_wr  = rd ? p.hb0  : p.hb1;
        float* __restrict__ el_wr = rd ? p.elb0 : p.elb1;

        // ---- gather: k = softmax-weighted aggregation (layout A) ----
        float acc[8] = {0.f,0.f,0.f,0.f,0.f,0.f,0.f,0.f};
        {
          const float erh = er_l[rA*NHEAD + hd];
          float sum = 0.f;
          int e = 0;
          for (; e + 4 <= degr; e += 4){
            const int sA = sbase + eptr[e+0];
            const int sB = sbase + eptr[e+1];
            const int sC = sbase + eptr[e+2];
            const int sD = sbase + eptr[e+3];
            const float eA = el_rd[sA*NHEAD + hd];
            const float eB = el_rd[sB*NHEAD + hd];
            const float eC = el_rd[sC*NHEAD + hd];
            const float eD = el_rd[sD*NHEAD + hd];
            const float4 a0 = *reinterpret_cast<const float4*>(h_rd + sA*HID + off8);
            const float4 a1 = *reinterpret_cast<const float4*>(h_rd + sA*HID + off8 + 4);
            const float4 b0 = *reinterpret_cast<const float4*>(h_rd + sB*HID + off8);
            const float4 b1 = *reinterpret_cast<const float4*>(h_rd + sB*HID + off8 + 4);
            const float4 c0 = *reinterpret_cast<const float4*>(h_rd + sC*HID + off8);
            const float4 c1 = *reinterpret_cast<const float4*>(h_rd + sC*HID + off8 + 4);
            const float4 d0 = *reinterpret_cast<const float4*>(h_rd + sD*HID + off8);
            const float4 d1 = *reinterpret_cast<const float4*>(h_rd + sD*HID + off8 + 4);
            const float xA = eA + erh, xB = eB + erh, xC = eC + erh, xD = eD + erh;
            const float wA = __expf(fminf(fmaxf(xA, 0.2f*xA), 30.f));
            const float wB = __expf(fminf(fmaxf(xB, 0.2f*xB), 30.f));
            const float wC = __expf(fminf(fmaxf(xC, 0.2f*xC), 30.f));
            const float wD = __expf(fminf(fmaxf(xD, 0.2f*xD), 30.f));
            sum += (wA + wB) + (wC + wD);
            acc8(acc, wA, a0, a1); acc8(acc, wB, b0, b1);
            acc8(acc, wC, c0, c1); acc8(acc, wD, d0, d1);
          }
          for (; e < degr; ++e){
            const int sA = sbase + eptr[e];
            const float eA = el_rd[sA*NHEAD + hd];
            const float4 a0 = *reinterpret_cast<const float4*>(h_rd + sA*HID + off8);
            const float4 a1 = *reinterpret_cast<const float4*>(h_rd + sA*HID + off8 + 4);
            const float xA = eA + erh;
            const float wA = __expf(fminf(fmaxf(xA, 0.2f*xA), 30.f));
            sum += wA;
            acc8(acc, wA, a0, a1);
          }
          const float inv = 1.f / (sum + 1e-16f);
          #pragma unroll
          for (int i=0;i<8;++i) acc[i] *= inv;
        }

        // ---- RK4 register update ----
        const bool is5 = (st == 3) && (j == 4);
        float nxt[8];
        if (j == 1){
          #pragma unroll
          for (int i=0;i<8;++i){ ya8[i] = fmaf(DT/6.f, acc[i], yb8[i]);
                                 nxt[i] = fmaf(0.5f*DT, acc[i], yb8[i]); }
        } else if (j == 2){
          #pragma unroll
          for (int i=0;i<8;++i){ ya8[i] = fmaf(DT/3.f, acc[i], ya8[i]);
                                 nxt[i] = fmaf(0.5f*DT, acc[i], yb8[i]); }
        } else if (j == 3){
          #pragma unroll
          for (int i=0;i<8;++i){ ya8[i] = fmaf(DT/3.f, acc[i], ya8[i]);
                                 nxt[i] = fmaf(DT, acc[i], yb8[i]); }
        } else {
          #pragma unroll
          for (int i=0;i<8;++i) nxt[i] = fmaf(DT/6.f, acc[i], ya8[i]);
          if (!is5){
            #pragma unroll
            for (int i=0;i<8;++i) yb8[i] = nxt[i];
          }
        }

        // next eval point -> yt (layout A); prev-stage yt readers finished
        // before the last grid_bar's __syncthreads
        *reinterpret_cast<float4*>(yt + rA*HID + off8)     = make_float4(nxt[0],nxt[1],nxt[2],nxt[3]);
        *reinterpret_cast<float4*>(yt + rA*HID + off8 + 4) = make_float4(nxt[4],nxt[5],nxt[6],nxt[7]);

        if (!is5){
          __syncthreads();
          gemm_epi(Wl, yt, fg, rs, row0, h_wr, el_wr, er_l, al4, ar4);
          grid_bar(p.bar, NBLK_P * step); ++step;
          rd ^= 1;
          continue;
        }

        // ---- end of interval: optional GRU, LN, state handoff ----
        const bool last = (idx == SEQL-1);
        float z0[4], z1[4];
        if (idx > 0){
          load_W<PTHREADS>(Wl, p.w_W, tid);
          __syncthreads();                       // yt(y_new) + w_W ready
          gemm128<16>(Wl, yt, fg, rs, z0, z1);   // z = y_new @ w_W
          __syncthreads();                       // gemm reads done
          {
            const float x0 = p.inputs[((bA*SEQL + idx)*NNODE + nA)*2 + 0];
            const float x1 = p.inputs[((bA*SEQL + idx)*NNODE + nA)*2 + 1];
            float hv[8];
            #pragma unroll
            for (int i=0;i<8;++i) hv[i] = x0*wi0[i] + x1*wi1[i] + bi8[i];
            *reinterpret_cast<float4*>(yt + rA*HID + off8)     = make_float4(hv[0],hv[1],hv[2],hv[3]);
            *reinterpret_cast<float4*>(yt + rA*HID + off8 + 4) = make_float4(hv[4],hv[5],hv[6],hv[7]);
          }
          load_W<PTHREADS>(Wl, p.w_U, tid);
          __syncthreads();
          float u0[4], u1[4];
          gemm128<16>(Wl, yt, fg, rs, u0, u1);   // u = h_in @ w_U
          #pragma unroll
          for (int i=0;i<4;++i){
            z0[i] = tanhf(z0[i] + u0[i] + bb4[i]);
            z1[i] = tanhf(z1[i] + u1[i] + bb4[i]);
          }
        } else {
          __syncthreads();                       // yt(y_new) visible in F layout
          #pragma unroll
          for (int i=0;i<4;++i){
            z0[i] = yt[rs*HID + fg*4 + i];
            z1[i] = yt[(rs+16)*HID + fg*4 + i];
          }
        }
        // LayerNorm over 128 features (32 fg lanes)
        {
          float s0v=0.f,q0=0.f,s1v=0.f,q1=0.f;
          #pragma unroll
          for (int i=0;i<4;++i){ s0v+=z0[i]; q0+=z0[i]*z0[i]; s1v+=z1[i]; q1+=z1[i]*z1[i]; }
          #pragma unroll
          for (int off=1; off<32; off<<=1){
            s0v += __shfl_xor(s0v, off); q0 += __shfl_xor(q0, off);
            s1v += __shfl_xor(s1v, off); q1 += __shfl_xor(q1, off);
          }
          float mu0 = s0v*(1.f/HID), mu1 = s1v*(1.f/HID);
          float r0 = rsqrtf(q0*(1.f/HID) - mu0*mu0 + 1e-5f);
          float r1 = rsqrtf(q1*(1.f/HID) - mu1*mu1 + 1e-5f);
          #pragma unroll
          for (int i=0;i<4;++i){ z0[i] = (z0[i]-mu0)*r0; z1[i] = (z1[i]-mu1)*r1; }
        }
        __syncthreads();                         // all yt readers done
        *reinterpret_cast<float4*>(yt + rs*HID + fg*4)      = make_float4(z0[0],z0[1],z0[2],z0[3]);
        *reinterpret_cast<float4*>(yt + (rs+16)*HID + fg*4) = make_float4(z1[0],z1[1],z1[2],z1[3]);
        if (last){
          *reinterpret_cast<float4*>(p.y_out + rowF0*HID + fg*4) = make_float4(z0[0],z0[1],z0[2],z0[3]);
          *reinterpret_cast<float4*>(p.y_out + rowF1*HID + fg*4) = make_float4(z1[0],z1[1],z1[2],z1[3]);
          // final stage: no more barriers; all blocks exit uniformly
        } else {
          if (idx > 0) load_W<PTHREADS>(Wl, p.w_gat, tid);  // restore resident w_gat
          __syncthreads();
          #pragma unroll
          for (int i=0;i<8;++i) yb8[i] = yt[rA*HID + off8 + i];  // new y state
          gemm_epi(Wl, yt, fg, rs, row0, h_wr, el_wr, er_l, al4, ar4);
          grid_bar(p.bar, NBLK_P * step); ++step;
          rd ^= 1;
        }
      }
    }
  }
}

// out = tanh(ret @ w_o1 + b_o1) @ w_o2 + b_o2, fp32 output
__global__ void __launch_bounds__(256, 2) out_kernel(
    const float* __restrict__ y_base,
    const float* __restrict__ w_o1, const float* __restrict__ b_o1,
    const float* __restrict__ w_o2, const float* __restrict__ b_o2,
    float* __restrict__ out)
{
  __shared__ float Wl[HID*HID];
  __shared__ float yt[ORPB*HID];
  const int tid = threadIdx.x;
  const int row0 = blockIdx.x * ORPB;
  const int rA = tid >> 4, tA = tid & 15;
  const int rowA = row0 + rA;
  {
    float4 v0 = *reinterpret_cast<const float4*>(y_base + rowA*HID + tA*8);
    float4 v1 = *reinterpret_cast<const float4*>(y_base + rowA*HID + tA*8 + 4);
    *reinterpret_cast<float4*>(yt + rA*HID + tA*8)     = v0;
    *reinterpret_cast<float4*>(yt + rA*HID + tA*8 + 4) = v1;
  }
  load_W<256>(Wl, w_o1, tid);
  __syncthreads();
  const int fg = tid & 31, rs = tid >> 5;
  float t0[4], t1[4];
  gemm128<8>(Wl, yt, fg, rs, t0, t1);
  #pragma unroll
  for (int i=0;i<4;++i){
    float bb = b_o1[fg*4+i];
    t0[i] = tanhf(t0[i] + bb);
    t1[i] = tanhf(t1[i] + bb);
  }
  __syncthreads();
  *reinterpret_cast<float4*>(yt + rs*HID + fg*4)     = make_float4(t0[0],t0[1],t0[2],t0[3]);
  *reinterpret_cast<float4*>(yt + (rs+8)*HID + fg*4) = make_float4(t1[0],t1[1],t1[2],t1[3]);
  load_W<256>(Wl, w_o2, tid);
  __syncthreads();
  float o0[4], o1[4];
  gemm128<8>(Wl, yt, fg, rs, o0, o1);
  const int rowF0 = row0 + rs, rowF1 = row0 + rs + 8;
  *reinterpret_cast<float4*>(out + rowF0*HID + fg*4) =
      make_float4(o0[0]+b_o2[fg*4+0], o0[1]+b_o2[fg*4+1], o0[2]+b_o2[fg*4+2], o0[3]+b_o2[fg*4+3]);
  *reinterpret_cast<float4*>(out + rowF1*HID + fg*4) =
      make_float4(o1[0]+b_o2[fg*4+0], o1[1]+b_o2[fg*4+1], o1[2]+b_o2[fg*4+2], o1[3]+b_o2[fg*4+3]);
}

extern "C" void kernel_launch(void* const* d_in, const int* in_sizes, int n_in,
                              void* d_out, int out_size, void* d_ws, size_t ws_size,
                              hipStream_t stream)
{
  const float* inputs = (const float*)d_in[0];
  const int* src      = (const int*)d_in[1];
  const int* dst      = (const int*)d_in[2];
  const float* w_in   = (const float*)d_in[3];
  const float* b_in   = (const float*)d_in[4];
  const float* w_gat  = (const float*)d_in[5];
  const float* a_l    = (const float*)d_in[6];
  const float* a_r    = (const float*)d_in[7];
  const float* w_W    = (const float*)d_in[8];
  const float* b_W    = (const float*)d_in[9];
  const float* w_U    = (const float*)d_in[10];
  const float* b_U    = (const float*)d_in[11];
  const float* w_o1   = (const float*)d_in[12];
  const float* b_o1   = (const float*)d_in[13];
  const float* w_o2   = (const float*)d_in[14];
  const float* b_o2   = (const float*)d_in[15];

  float* F = reinterpret_cast<float*>(d_ws);
  const size_t RH = (size_t)NROWS * HID;    // 1,024,000
  const size_t RE = (size_t)NROWS * NHEAD;  // 64,000
  size_t need = (3*RH + 2*RE)*sizeof(float) + (size_t)(1024 + NEDGE + 16)*sizeof(int);
  if (ws_size < need) return;

  float* hb0   = F;
  float* hb1   = F + RH;
  float* y_out = F + 2*RH;
  float* elb0  = F + 3*RH;
  float* elb1  = elb0 + RE;
  int* I = reinterpret_cast<int*>(elb1 + RE);
  int* row_start = I;
  int* edge_src  = I + 1024;
  int* bar       = I + 1024 + NEDGE;

  csr_kernel<<<1, 1024, 0, stream>>>(src, dst, row_start, edge_src, bar);

  PArgs pa;
  pa.hb0 = hb0; pa.elb0 = elb0; pa.hb1 = hb1; pa.elb1 = elb1; pa.y_out = y_out;
  pa.row_start = row_start; pa.edge_src = edge_src;
  pa.w_gat = w_gat; pa.a_l = a_l; pa.a_r = a_r;
  pa.inputs = inputs; pa.w_in = w_in; pa.b_in = b_in;
  pa.w_W = w_W; pa.b_W = b_W; pa.w_U = w_U; pa.b_U = b_U;
  pa.bar = bar;

  persist<<<NBLK_P, PTHREADS, 0, stream>>>(pa);

  out_kernel<<<NBLK_O, 256, 0, stream>>>(y_out, w_o1, b_o1, w_o2, b_o2, (float*)d_out);
}

// Round 6
// 5857.198 us; speedup vs baseline: 1.2421x; 1.2421x over previous
//
#include <hip/hip_runtime.h>

#define NNODE 1000
#define NBATCH 8
#define SEQL 12
#define NHEAD 8
#define DHEAD 16
#define HID 128
#define NEDGE 16000
#define NROWS (NBATCH*NNODE)   // 8000
#define RPB 32                 // rows per persistent block
#define NBLK_P 256             // 8 xcd-groups x 32 slots; 1 block/CU
#define PTHREADS 1024
#define ORPB 16
#define NBLK_O (NROWS/ORPB)    // 500
#define DT 0.25f
#define ECAP 768               // LDS edge cache (block mean 512)
#define SPIN_LIMIT 10000ULL    // 100 us escape hatch (finite wrong-run, not hang)

// ---- grid barrier: monotonic epoch counter, agent-scope atomics ----
__device__ __forceinline__ void grid_bar(int* bar, int target){
  __syncthreads();
  if (threadIdx.x == 0){
    __threadfence();
    __hip_atomic_fetch_add(bar, 1, __ATOMIC_RELEASE, __HIP_MEMORY_SCOPE_AGENT);
    unsigned long long t0 = __builtin_amdgcn_s_memrealtime();
    while (__hip_atomic_load(bar, __ATOMIC_RELAXED, __HIP_MEMORY_SCOPE_AGENT) < target){
      __builtin_amdgcn_s_sleep(2);
      if (__builtin_amdgcn_s_memrealtime() - t0 > SPIN_LIMIT) break;
    }
    __threadfence();
  }
  __syncthreads();
}

// copy a 128x128 fp32 matrix global->LDS, NT threads
template<int NT>
__device__ __forceinline__ void load_W(float* Wl, const float* g, int tid){
  #pragma unroll
  for (int c = 0; c < (HID*HID/4)/NT; ++c){
    int e = (c*NT + tid)*4;
    *reinterpret_cast<float4*>(Wl + e) = *reinterpret_cast<const float4*>(g + e);
  }
}

// one row: o[j] = sum_k yt[rs][k]*Wl[k][fg*4+j]
__device__ __forceinline__ void gemm128_1(const float* Wl, const float* yt, int fg, int rs,
                                          float o[4]){
  float a0[4]={0.f,0.f,0.f,0.f};
  #pragma unroll 4
  for (int k=0;k<HID;k+=4){
    float4 ya = *reinterpret_cast<const float4*>(yt + rs*HID + k);
    #pragma unroll
    for (int kk=0;kk<4;++kk){
      const float* wr = Wl + (k+kk)*HID + fg*4;
      float av = (&ya.x)[kk];
      #pragma unroll
      for (int i=0;i<4;++i) a0[i] = fmaf(wr[i], av, a0[i]);
    }
  }
  #pragma unroll
  for (int i=0;i<4;++i) o[i]=a0[i];
}

// two rows (rs, rs+RSTEP) — used by out_kernel
template<int RSTEP>
__device__ __forceinline__ void gemm128(const float* Wl, const float* yt, int fg, int rs,
                                        float o0[4], float o1[4]){
  float a0[4]={0.f,0.f,0.f,0.f}, a1[4]={0.f,0.f,0.f,0.f};
  #pragma unroll 4
  for (int k=0;k<HID;k+=4){
    float4 ya = *reinterpret_cast<const float4*>(yt + rs*HID + k);
    float4 yb = *reinterpret_cast<const float4*>(yt + (rs+RSTEP)*HID + k);
    #pragma unroll
    for (int kk=0;kk<4;++kk){
      const float* wr = Wl + (k+kk)*HID + fg*4;
      float av = (&ya.x)[kk];
      float bv = (&yb.x)[kk];
      #pragma unroll
      for (int i=0;i<4;++i){
        float w = wr[i];
        a0[i] = fmaf(w, av, a0[i]);
        a1[i] = fmaf(w, bv, a1[i]);
      }
    }
  }
  #pragma unroll
  for (int i=0;i<4;++i){ o0[i]=a0[i]; o1[i]=a1[i]; }
}

// acc[0..7] += wt * {v0.xyzw, v1.xyzw}
__device__ __forceinline__ void acc8(float acc[8], float wt, const float4& v0, const float4& v1){
  acc[0]=fmaf(wt,v0.x,acc[0]); acc[1]=fmaf(wt,v0.y,acc[1]);
  acc[2]=fmaf(wt,v0.z,acc[2]); acc[3]=fmaf(wt,v0.w,acc[3]);
  acc[4]=fmaf(wt,v1.x,acc[4]); acc[5]=fmaf(wt,v1.y,acc[5]);
  acc[6]=fmaf(wt,v1.z,acc[6]); acc[7]=fmaf(wt,v1.w,acc[7]);
}

// h = yt[rs] @ Wl (one row/thread); h + el to global, own-row er to LDS.
__device__ __forceinline__ void gemm_epi(const float* Wl, const float* yt,
    int fg, int rs, int rowF, bool actF,
    float* __restrict__ h_wr, float* __restrict__ el_wr, float* er_l,
    const float al4[4], const float ar4[4])
{
  float o[4];
  gemm128_1(Wl, yt, fg, rs, o);
  if (actF)
    *reinterpret_cast<float4*>(h_wr + rowF*HID + fg*4) = make_float4(o[0],o[1],o[2],o[3]);
  const int hd2 = fg >> 2;
  float el=0.f, er=0.f;
  #pragma unroll
  for (int i=0;i<4;++i){
    el = fmaf(o[i], al4[i], el); er = fmaf(o[i], ar4[i], er);
  }
  el += __shfl_xor(el,1); el += __shfl_xor(el,2);
  er += __shfl_xor(er,1); er += __shfl_xor(er,2);
  if ((fg & 3) == 0 && actF){
    el_wr[rowF*NHEAD + hd2] = el;
    er_l[rs*NHEAD + hd2]    = er;
  }
}

// Build CSR (edges sorted by dst); also zero the grid-barrier counter.
__global__ void csr_kernel(const int* __restrict__ src, const int* __restrict__ dst,
                           int* __restrict__ row_start, int* __restrict__ edge_src,
                           int* __restrict__ bar){
  __shared__ int cnt[1024];
  __shared__ int scanb[1024];
  __shared__ int cur[1024];
  int tid = threadIdx.x;
  if (tid == 0) bar[0] = 0;
  cnt[tid] = 0;
  __syncthreads();
  for (int e = tid; e < NEDGE; e += 1024) atomicAdd(&cnt[dst[e]], 1);
  __syncthreads();
  int v = cnt[tid];
  scanb[tid] = v;
  __syncthreads();
  for (int off=1; off<1024; off<<=1){
    int t = (tid >= off) ? scanb[tid-off] : 0;
    __syncthreads();
    scanb[tid] += t;
    __syncthreads();
  }
  int incl = scanb[tid];
  if (tid < NNODE){ cur[tid] = incl - v; row_start[tid+1] = incl; }
  if (tid == 0) row_start[0] = 0;
  __syncthreads();
  for (int e = tid; e < NEDGE; e += 1024){
    int d = dst[e];
    int pos = atomicAdd(&cur[d], 1);
    edge_src[pos] = src[e];
  }
}

struct PArgs {
  float* hb0; float* elb0; float* hb1; float* elb1; float* y_out;
  const int* row_start; const int* edge_src;
  const float* w_gat; const float* a_l; const float* a_r;
  const float* inputs; const float* w_in; const float* b_in;
  const float* w_W; const float* b_W; const float* w_U; const float* b_U;
  int* bar;
};

__global__ void __launch_bounds__(PTHREADS, 4) persist(PArgs p)
{
  __shared__ float Wl[HID*HID];      // 64 KB — w_gat resident except around GRU
  __shared__ float yt[RPB*HID];      // 16 KB
  __shared__ int   esrc_l[ECAP];     // 3 KB
  __shared__ int   eoff[RPB+1];
  __shared__ int   degs_s[RPB];
  __shared__ float er_l[RPB*NHEAD];  // ~86 KB total -> 1 block/CU, 16 waves

  const int tid  = threadIdx.x;
  // XCD-aware mapping: blockIdx%8 -> XCD (round-robin heuristic) -> batch.
  // Each XCD's gather read-set becomes its own batch's h slice (512 KB).
  const int xcd   = blockIdx.x & 7;            // = batch index
  const int slot  = blockIdx.x >> 3;           // 0..31
  const int row0  = xcd * NNODE + slot * RPB;
  const int nrows = (slot == 31) ? (NNODE - 31*RPB) : RPB;   // 8 or 32
  // layout A: 16 threads x 2 edge-segments per row
  const int tA = tid & 15, seg = (tid >> 4) & 1, rA = tid >> 5;
  const bool actA = rA < nrows;
  const int nA     = slot*RPB + rA;            // node within batch
  const int nAs    = actA ? nA : 0;            // safe index for guarded loads
  const int sbase  = xcd * NNODE;
  const int hd   = tA >> 1;
  const int off8 = tA * 8;
  // layout F: 32 col-groups x 32 rows (1 row/thread)
  const int fg = tid & 31, rs = tid >> 5;
  const bool actF = rs < nrows;
  const int rowF = row0 + rs;
  const int hd2 = fg >> 2, db = (fg & 3) * 4;

  // ---- one-time: per-block edge cache ----
  int s0r = 0, degr = 0;
  if (actA){ s0r = p.row_start[nA]; degr = p.row_start[nA+1] - s0r; }
  if ((tid & 31) == 0) degs_s[rA] = degr;
  __syncthreads();
  if (tid == 0){
    int o = 0;
    #pragma unroll
    for (int r = 0; r < RPB; ++r){ eoff[r] = o; o += degs_s[r]; }
    eoff[RPB] = o;
  }
  __syncthreads();
  const int* eptr;
  if (eoff[RPB] <= ECAP){
    const int eb = eoff[rA];
    for (int e = tA + 16*seg; e < degr; e += 32) esrc_l[eb + e] = p.edge_src[s0r + e];
    eptr = esrc_l + eb;
  } else {
    eptr = p.edge_src + s0r;   // statistically never; correctness fallback
  }

  // ---- one-time: per-thread constants ----
  float wi0[8], wi1[8], bi8[8];
  #pragma unroll
  for (int i=0;i<8;++i){
    int f = off8 + i;
    wi0[i] = p.w_in[f]; wi1[i] = p.w_in[HID+f]; bi8[i] = p.b_in[f];
  }
  float al4[4], ar4[4], bb4[4];
  #pragma unroll
  for (int i=0;i<4;++i){
    al4[i] = p.a_l[hd2*DHEAD + db + i];
    ar4[i] = p.a_r[hd2*DHEAD + db + i];
    bb4[i] = p.b_W[fg*4+i] + p.b_U[fg*4+i];
  }

  load_W<PTHREADS>(Wl, p.w_gat, tid);

  // ---- init: y0 = inputs[:,0]@w_in + b_in ----
  float yb8[8], ya8[8];
  {
    const float x0 = p.inputs[((xcd*SEQL + 0)*NNODE + nAs)*2 + 0];
    const float x1 = p.inputs[((xcd*SEQL + 0)*NNODE + nAs)*2 + 1];
    #pragma unroll
    for (int i=0;i<8;++i) yb8[i] = x0*wi0[i] + x1*wi1[i] + bi8[i];
    if (seg == 0){
      *reinterpret_cast<float4*>(yt + rA*HID + off8)     = make_float4(yb8[0],yb8[1],yb8[2],yb8[3]);
      *reinterpret_cast<float4*>(yt + rA*HID + off8 + 4) = make_float4(yb8[4],yb8[5],yb8[6],yb8[7]);
    }
  }
  __syncthreads();     // yt, Wl, esrc_l staged
  gemm_epi(Wl, yt, fg, rs, rowF, actF, p.hb0, p.elb0, er_l, al4, ar4);

  int step = 1;
  grid_bar(p.bar, NBLK_P * step); ++step;

  // per-segment edge range (contiguous halves)
  const int half0 = (degr + 1) >> 1;
  const int e_lo = seg ? half0 : 0;
  const int e_hi = seg ? degr  : half0;

  int rd = 0;
  for (int idx = 0; idx < SEQL; ++idx){
    for (int st = 0; st < 4; ++st){
      for (int j = 1; j <= 4; ++j){
        const float* __restrict__ h_rd  = rd ? p.hb1  : p.hb0;
        const float* __restrict__ el_rd = rd ? p.elb1 : p.elb0;
        float* __restrict__ h_wr  = rd ? p.hb0  : p.hb1;
        float* __restrict__ el_wr = rd ? p.elb0 : p.elb1;

        // ---- gather: softmax-weighted aggregation (layout A, 2 segs/row) ----
        float acc[8] = {0.f,0.f,0.f,0.f,0.f,0.f,0.f,0.f};
        float sum = 0.f;
        {
          const float erh = er_l[rA*NHEAD + hd];
          int e = e_lo;
          for (; e + 4 <= e_hi; e += 4){
            const int sA = sbase + eptr[e+0];
            const int sB = sbase + eptr[e+1];
            const int sC = sbase + eptr[e+2];
            const int sD = sbase + eptr[e+3];
            const float eA = el_rd[sA*NHEAD + hd];
            const float eB = el_rd[sB*NHEAD + hd];
            const float eC = el_rd[sC*NHEAD + hd];
            const float eD = el_rd[sD*NHEAD + hd];
            const float4 a0 = *reinterpret_cast<const float4*>(h_rd + sA*HID + off8);
            const float4 a1 = *reinterpret_cast<const float4*>(h_rd + sA*HID + off8 + 4);
            const float4 b0 = *reinterpret_cast<const float4*>(h_rd + sB*HID + off8);
            const float4 b1 = *reinterpret_cast<const float4*>(h_rd + sB*HID + off8 + 4);
            const float4 c0 = *reinterpret_cast<const float4*>(h_rd + sC*HID + off8);
            const float4 c1 = *reinterpret_cast<const float4*>(h_rd + sC*HID + off8 + 4);
            const float4 d0 = *reinterpret_cast<const float4*>(h_rd + sD*HID + off8);
            const float4 d1 = *reinterpret_cast<const float4*>(h_rd + sD*HID + off8 + 4);
            const float xA = eA + erh, xB = eB + erh, xC = eC + erh, xD = eD + erh;
            const float wA = __expf(fminf(fmaxf(xA, 0.2f*xA), 30.f));
            const float wB = __expf(fminf(fmaxf(xB, 0.2f*xB), 30.f));
            const float wC = __expf(fminf(fmaxf(xC, 0.2f*xC), 30.f));
            const float wD = __expf(fminf(fmaxf(xD, 0.2f*xD), 30.f));
            sum += (wA + wB) + (wC + wD);
            acc8(acc, wA, a0, a1); acc8(acc, wB, b0, b1);
            acc8(acc, wC, c0, c1); acc8(acc, wD, d0, d1);
          }
          for (; e < e_hi; ++e){
            const int sA = sbase + eptr[e];
            const float eA = el_rd[sA*NHEAD + hd];
            const float4 a0 = *reinterpret_cast<const float4*>(h_rd + sA*HID + off8);
            const float4 a1 = *reinterpret_cast<const float4*>(h_rd + sA*HID + off8 + 4);
            const float xA = eA + erh;
            const float wA = __expf(fminf(fmaxf(xA, 0.2f*xA), 30.f));
            sum += wA;
            acc8(acc, wA, a0, a1);
          }
        }
        // combine the two segments (lane ^ 16 = same row, other segment)
        sum += __shfl_xor(sum, 16);
        #pragma unroll
        for (int i=0;i<8;++i) acc[i] += __shfl_xor(acc[i], 16);
        const float inv = 1.f / (sum + 1e-16f);
        #pragma unroll
        for (int i=0;i<8;++i) acc[i] *= inv;

        // ---- RK4 register update (duplicated in both segs, identical) ----
        const bool is5 = (st == 3) && (j == 4);
        float nxt[8];
        if (j == 1){
          #pragma unroll
          for (int i=0;i<8;++i){ ya8[i] = fmaf(DT/6.f, acc[i], yb8[i]);
                                 nxt[i] = fmaf(0.5f*DT, acc[i], yb8[i]); }
        } else if (j == 2){
          #pragma unroll
          for (int i=0;i<8;++i){ ya8[i] = fmaf(DT/3.f, acc[i], ya8[i]);
                                 nxt[i] = fmaf(0.5f*DT, acc[i], yb8[i]); }
        } else if (j == 3){
          #pragma unroll
          for (int i=0;i<8;++i){ ya8[i] = fmaf(DT/3.f, acc[i], ya8[i]);
                                 nxt[i] = fmaf(DT, acc[i], yb8[i]); }
        } else {
          #pragma unroll
          for (int i=0;i<8;++i) nxt[i] = fmaf(DT/6.f, acc[i], ya8[i]);
          if (!is5){
            #pragma unroll
            for (int i=0;i<8;++i) yb8[i] = nxt[i];
          }
        }

        if (seg == 0){
          *reinterpret_cast<float4*>(yt + rA*HID + off8)     = make_float4(nxt[0],nxt[1],nxt[2],nxt[3]);
          *reinterpret_cast<float4*>(yt + rA*HID + off8 + 4) = make_float4(nxt[4],nxt[5],nxt[6],nxt[7]);
        }

        if (!is5){
          __syncthreads();
          gemm_epi(Wl, yt, fg, rs, rowF, actF, h_wr, el_wr, er_l, al4, ar4);
          grid_bar(p.bar, NBLK_P * step); ++step;
          rd ^= 1;
          continue;
        }

        // ---- end of interval: optional GRU, LN, state handoff ----
        const bool last = (idx == SEQL-1);
        float z[4];
        if (idx > 0){
          load_W<PTHREADS>(Wl, p.w_W, tid);
          __syncthreads();                       // yt(y_new) + w_W ready
          gemm128_1(Wl, yt, fg, rs, z);          // z = y_new @ w_W
          __syncthreads();                       // gemm reads done
          {
            const float x0 = p.inputs[((xcd*SEQL + idx)*NNODE + nAs)*2 + 0];
            const float x1 = p.inputs[((xcd*SEQL + idx)*NNODE + nAs)*2 + 1];
            float hv[8];
            #pragma unroll
            for (int i=0;i<8;++i) hv[i] = x0*wi0[i] + x1*wi1[i] + bi8[i];
            if (seg == 0){
              *reinterpret_cast<float4*>(yt + rA*HID + off8)     = make_float4(hv[0],hv[1],hv[2],hv[3]);
              *reinterpret_cast<float4*>(yt + rA*HID + off8 + 4) = make_float4(hv[4],hv[5],hv[6],hv[7]);
            }
          }
          load_W<PTHREADS>(Wl, p.w_U, tid);
          __syncthreads();
          float u[4];
          gemm128_1(Wl, yt, fg, rs, u);          // u = h_in @ w_U
          #pragma unroll
          for (int i=0;i<4;++i) z[i] = tanhf(z[i] + u[i] + bb4[i]);
        } else {
          __syncthreads();                       // yt(y_new) visible in F layout
          #pragma unroll
          for (int i=0;i<4;++i) z[i] = yt[rs*HID + fg*4 + i];
        }
        // LayerNorm over 128 features (32 fg lanes)
        {
          float sv=0.f, qv=0.f;
          #pragma unroll
          for (int i=0;i<4;++i){ sv+=z[i]; qv+=z[i]*z[i]; }
          #pragma unroll
          for (int off=1; off<32; off<<=1){
            sv += __shfl_xor(sv, off); qv += __shfl_xor(qv, off);
          }
          float mu = sv*(1.f/HID);
          float r  = rsqrtf(qv*(1.f/HID) - mu*mu + 1e-5f);
          #pragma unroll
          for (int i=0;i<4;++i) z[i] = (z[i]-mu)*r;
        }
        __syncthreads();                         // all yt readers done
        *reinterpret_cast<float4*>(yt + rs*HID + fg*4) = make_float4(z[0],z[1],z[2],z[3]);
        if (last){
          if (actF)
            *reinterpret_cast<float4*>(p.y_out + rowF*HID + fg*4) = make_float4(z[0],z[1],z[2],z[3]);
          // final stage: no more barriers; all blocks exit uniformly
        } else {
          if (idx > 0) load_W<PTHREADS>(Wl, p.w_gat, tid);  // restore resident w_gat
          __syncthreads();
          #pragma unroll
          for (int i=0;i<8;++i) yb8[i] = yt[rA*HID + off8 + i];  // new y state
          gemm_epi(Wl, yt, fg, rs, rowF, actF, h_wr, el_wr, er_l, al4, ar4);
          grid_bar(p.bar, NBLK_P * step); ++step;
          rd ^= 1;
        }
      }
    }
  }
}

// out = tanh(ret @ w_o1 + b_o1) @ w_o2 + b_o2, fp32 output
__global__ void __launch_bounds__(256, 2) out_kernel(
    const float* __restrict__ y_base,
    const float* __restrict__ w_o1, const float* __restrict__ b_o1,
    const float* __restrict__ w_o2, const float* __restrict__ b_o2,
    float* __restrict__ out)
{
  __shared__ float Wl[HID*HID];
  __shared__ float yt[ORPB*HID];
  const int tid = threadIdx.x;
  const int row0 = blockIdx.x * ORPB;
  const int rA = tid >> 4, tA = tid & 15;
  const int rowA = row0 + rA;
  {
    float4 v0 = *reinterpret_cast<const float4*>(y_base + rowA*HID + tA*8);
    float4 v1 = *reinterpret_cast<const float4*>(y_base + rowA*HID + tA*8 + 4);
    *reinterpret_cast<float4*>(yt + rA*HID + tA*8)     = v0;
    *reinterpret_cast<float4*>(yt + rA*HID + tA*8 + 4) = v1;
  }
  load_W<256>(Wl, w_o1, tid);
  __syncthreads();
  const int fg = tid & 31, rs = tid >> 5;
  float t0[4], t1[4];
  gemm128<8>(Wl, yt, fg, rs, t0, t1);
  #pragma unroll
  for (int i=0;i<4;++i){
    float bb = b_o1[fg*4+i];
    t0[i] = tanhf(t0[i] + bb);
    t1[i] = tanhf(t1[i] + bb);
  }
  __syncthreads();
  *reinterpret_cast<float4*>(yt + rs*HID + fg*4)     = make_float4(t0[0],t0[1],t0[2],t0[3]);
  *reinterpret_cast<float4*>(yt + (rs+8)*HID + fg*4) = make_float4(t1[0],t1[1],t1[2],t1[3]);
  load_W<256>(Wl, w_o2, tid);
  __syncthreads();
  float o0[4], o1[4];
  gemm128<8>(Wl, yt, fg, rs, o0, o1);
  const int rowF0 = row0 + rs, rowF1 = row0 + rs + 8;
  *reinterpret_cast<float4*>(out + rowF0*HID + fg*4) =
      make_float4(o0[0]+b_o2[fg*4+0], o0[1]+b_o2[fg*4+1], o0[2]+b_o2[fg*4+2], o0[3]+b_o2[fg*4+3]);
  *reinterpret_cast<float4*>(out + rowF1*HID + fg*4) =
      make_float4(o1[0]+b_o2[fg*4+0], o1[1]+b_o2[fg*4+1], o1[2]+b_o2[fg*4+2], o1[3]+b_o2[fg*4+3]);
}

extern "C" void kernel_launch(void* const* d_in, const int* in_sizes, int n_in,
                              void* d_out, int out_size, void* d_ws, size_t ws_size,
                              hipStream_t stream)
{
  const float* inputs = (const float*)d_in[0];
  const int* src      = (const int*)d_in[1];
  const int* dst      = (const int*)d_in[2];
  const float* w_in   = (const float*)d_in[3];
  const float* b_in   = (const float*)d_in[4];
  const float* w_gat  = (const float*)d_in[5];
  const float* a_l    = (const float*)d_in[6];
  const float* a_r    = (const float*)d_in[7];
  const float* w_W    = (const float*)d_in[8];
  const float* b_W    = (const float*)d_in[9];
  const float* w_U    = (const float*)d_in[10];
  const float* b_U    = (const float*)d_in[11];
  const float* w_o1   = (const float*)d_in[12];
  const float* b_o1   = (const float*)d_in[13];
  const float* w_o2   = (const float*)d_in[14];
  const float* b_o2   = (const float*)d_in[15];

  float* F = reinterpret_cast<float*>(d_ws);
  const size_t RH = (size_t)NROWS * HID;    // 1,024,000
  const size_t RE = (size_t)NROWS * NHEAD;  // 64,000
  size_t need = (3*RH + 2*RE)*sizeof(float) + (size_t)(1024 + NEDGE + 16)*sizeof(int);
  if (ws_size < need) return;

  float* hb0   = F;
  float* hb1   = F + RH;
  float* y_out = F + 2*RH;
  float* elb0  = F + 3*RH;
  float* elb1  = elb0 + RE;
  int* I = reinterpret_cast<int*>(elb1 + RE);
  int* row_start = I;
  int* edge_src  = I + 1024;
  int* bar       = I + 1024 + NEDGE;

  csr_kernel<<<1, 1024, 0, stream>>>(src, dst, row_start, edge_src, bar);

  PArgs pa;
  pa.hb0 = hb0; pa.elb0 = elb0; pa.hb1 = hb1; pa.elb1 = elb1; pa.y_out = y_out;
  pa.row_start = row_start; pa.edge_src = edge_src;
  pa.w_gat = w_gat; pa.a_l = a_l; pa.a_r = a_r;
  pa.inputs = inputs; pa.w_in = w_in; pa.b_in = b_in;
  pa.w_W = w_W; pa.b_W = b_W; pa.w_U = w_U; pa.b_U = b_U;
  pa.bar = bar;

  persist<<<NBLK_P, PTHREADS, 0, stream>>>(pa);

  out_kernel<<<NBLK_O, 256, 0, stream>>>(y_out, w_o1, b_o1, w_o2, b_o2, (float*)d_out);
}

// Round 7
// 5722.746 us; speedup vs baseline: 1.2713x; 1.0235x over previous
//
#include <hip/hip_runtime.h>

#define NNODE 1000
#define NBATCH 8
#define SEQL 12
#define NHEAD 8
#define DHEAD 16
#define HID 128
#define NEDGE 16000
#define NROWS (NBATCH*NNODE)   // 8000
#define RPB 32                 // rows per persistent block
#define NBLK_P 256             // 8 batch-groups x 32 slots; 1 block/CU
#define NBLK_B 32              // blocks per batch = barrier width
#define BARSTRIDE 64           // ints between per-batch counters (256 B)
#define PTHREADS 1024
#define ORPB 16
#define NBLK_O (NROWS/ORPB)    // 500
#define DT 0.25f
#define ECAP 768               // LDS edge cache (block mean 512)
#define SPIN_LIMIT 100000ULL   // 1 ms escape hatch (finite wrong-run, not hang)

// ---- per-batch barrier: monotonic epoch counter, agent-scope atomics ----
// Correctness does not depend on block->XCD placement: participants are the
// 32 blocks of one batch (the only blocks with data dependencies), and the
// release/acquire fences are agent-scope.
__device__ __forceinline__ void grid_bar(int* bar, int target){
  __syncthreads();
  if (threadIdx.x == 0){
    __threadfence();   // release: wbl2 — block's h/el writes reach MALL
    __hip_atomic_fetch_add(bar, 1, __ATOMIC_RELEASE, __HIP_MEMORY_SCOPE_AGENT);
    unsigned long long t0 = __builtin_amdgcn_s_memrealtime();
    while (__hip_atomic_load(bar, __ATOMIC_RELAXED, __HIP_MEMORY_SCOPE_AGENT) < target){
      __builtin_amdgcn_s_sleep(2);
      if (__builtin_amdgcn_s_memrealtime() - t0 > SPIN_LIMIT) break;
    }
    __threadfence();   // acquire: inv L1/L2 — fresh reads from MALL
  }
  __syncthreads();
}

// copy a 128x128 fp32 matrix global->LDS, NT threads
template<int NT>
__device__ __forceinline__ void load_W(float* Wl, const float* g, int tid){
  #pragma unroll
  for (int c = 0; c < (HID*HID/4)/NT; ++c){
    int e = (c*NT + tid)*4;
    *reinterpret_cast<float4*>(Wl + e) = *reinterpret_cast<const float4*>(g + e);
  }
}

// one row, 8 cols: o[j] = sum_k yt[rs][k]*Wl[k][fg*8+j]
__device__ __forceinline__ void gemm128_8(const float* Wl, const float* yt, int fg, int rs,
                                          float o[8]){
  float a[8]={0.f,0.f,0.f,0.f,0.f,0.f,0.f,0.f};
  #pragma unroll 4
  for (int k=0;k<HID;k+=4){
    float4 ya = *reinterpret_cast<const float4*>(yt + rs*HID + k);
    #pragma unroll
    for (int kk=0;kk<4;++kk){
      const float* wr = Wl + (k+kk)*HID + fg*8;
      float av = (&ya.x)[kk];
      #pragma unroll
      for (int i=0;i<8;++i) a[i] = fmaf(wr[i], av, a[i]);
    }
  }
  #pragma unroll
  for (int i=0;i<8;++i) o[i]=a[i];
}

// two rows (rs, rs+RSTEP), 4 cols — used by out_kernel
template<int RSTEP>
__device__ __forceinline__ void gemm128(const float* Wl, const float* yt, int fg, int rs,
                                        float o0[4], float o1[4]){
  float a0[4]={0.f,0.f,0.f,0.f}, a1[4]={0.f,0.f,0.f,0.f};
  #pragma unroll 4
  for (int k=0;k<HID;k+=4){
    float4 ya = *reinterpret_cast<const float4*>(yt + rs*HID + k);
    float4 yb = *reinterpret_cast<const float4*>(yt + (rs+RSTEP)*HID + k);
    #pragma unroll
    for (int kk=0;kk<4;++kk){
      const float* wr = Wl + (k+kk)*HID + fg*4;
      float av = (&ya.x)[kk];
      float bv = (&yb.x)[kk];
      #pragma unroll
      for (int i=0;i<4;++i){
        float w = wr[i];
        a0[i] = fmaf(w, av, a0[i]);
        a1[i] = fmaf(w, bv, a1[i]);
      }
    }
  }
  #pragma unroll
  for (int i=0;i<4;++i){ o0[i]=a0[i]; o1[i]=a1[i]; }
}

// acc[0..7] += wt * {v0.xyzw, v1.xyzw}
__device__ __forceinline__ void acc8(float acc[8], float wt, const float4& v0, const float4& v1){
  acc[0]=fmaf(wt,v0.x,acc[0]); acc[1]=fmaf(wt,v0.y,acc[1]);
  acc[2]=fmaf(wt,v0.z,acc[2]); acc[3]=fmaf(wt,v0.w,acc[3]);
  acc[4]=fmaf(wt,v1.x,acc[4]); acc[5]=fmaf(wt,v1.y,acc[5]);
  acc[6]=fmaf(wt,v1.z,acc[6]); acc[7]=fmaf(wt,v1.w,acc[7]);
}

// h = yt[rsF] @ Wl (8 cols/thread); h + el to global, own-row er to LDS.
// Caller guards tid<512; no barriers inside.
__device__ __forceinline__ void gemm_epi8(const float* Wl, const float* yt,
    int fgF, int rsF, int rowF, bool actF,
    float* __restrict__ h_wr, float* __restrict__ el_wr, float* er_l,
    const float al8[8], const float ar8[8])
{
  float o[8];
  gemm128_8(Wl, yt, fgF, rsF, o);
  if (actF){
    *reinterpret_cast<float4*>(h_wr + rowF*HID + fgF*8)     = make_float4(o[0],o[1],o[2],o[3]);
    *reinterpret_cast<float4*>(h_wr + rowF*HID + fgF*8 + 4) = make_float4(o[4],o[5],o[6],o[7]);
  }
  const int head = fgF >> 1;
  float el=0.f, er=0.f;
  #pragma unroll
  for (int i=0;i<8;++i){
    el = fmaf(o[i], al8[i], el); er = fmaf(o[i], ar8[i], er);
  }
  el += __shfl_xor(el,1);
  er += __shfl_xor(er,1);
  if (!(fgF & 1) && actF){
    el_wr[rowF*NHEAD + head] = el;
    er_l[rsF*NHEAD + head]   = er;
  }
}

// Build CSR (edges sorted by dst); zero the 8 per-batch barrier counters.
__global__ void csr_kernel(const int* __restrict__ src, const int* __restrict__ dst,
                           int* __restrict__ row_start, int* __restrict__ edge_src,
                           int* __restrict__ bar){
  __shared__ int cnt[1024];
  __shared__ int scanb[1024];
  __shared__ int cur[1024];
  int tid = threadIdx.x;
  if (tid < NBATCH*BARSTRIDE) bar[tid] = 0;
  cnt[tid] = 0;
  __syncthreads();
  for (int e = tid; e < NEDGE; e += 1024) atomicAdd(&cnt[dst[e]], 1);
  __syncthreads();
  int v = cnt[tid];
  scanb[tid] = v;
  __syncthreads();
  for (int off=1; off<1024; off<<=1){
    int t = (tid >= off) ? scanb[tid-off] : 0;
    __syncthreads();
    scanb[tid] += t;
    __syncthreads();
  }
  int incl = scanb[tid];
  if (tid < NNODE){ cur[tid] = incl - v; row_start[tid+1] = incl; }
  if (tid == 0) row_start[0] = 0;
  __syncthreads();
  for (int e = tid; e < NEDGE; e += 1024){
    int d = dst[e];
    int pos = atomicAdd(&cur[d], 1);
    edge_src[pos] = src[e];
  }
}

struct PArgs {
  float* hb0; float* elb0; float* hb1; float* elb1; float* y_out;
  const int* row_start; const int* edge_src;
  const float* w_gat; const float* a_l; const float* a_r;
  const float* inputs; const float* w_in; const float* b_in;
  const float* w_W; const float* b_W; const float* w_U; const float* b_U;
  int* bar;
};

__global__ void __launch_bounds__(PTHREADS, 4) persist(PArgs p)
{
  __shared__ float Wl[HID*HID];      // 64 KB — w_gat resident except around GRU
  __shared__ float yt[RPB*HID];      // 16 KB
  __shared__ int   esrc_l[ECAP];     // 3 KB
  __shared__ int   eoff[RPB+1];
  __shared__ int   degs_s[RPB];
  __shared__ float er_l[RPB*NHEAD];  // ~86 KB total -> 1 block/CU, 16 waves

  const int tid  = threadIdx.x;
  // batch grouping doubles as XCD-locality heuristic (blockIdx%8 -> XCD)
  const int bat   = blockIdx.x & 7;            // batch index
  const int slot  = blockIdx.x >> 3;           // 0..31
  const int row0  = bat * NNODE + slot * RPB;
  const int nrows = (slot == 31) ? (NNODE - 31*RPB) : RPB;   // 8 or 32
  int* const bar_b = p.bar + bat * BARSTRIDE;
  // layout A (gather): 16 threads x 2 edge-segments per row, 32 rows
  const int tA = tid & 15, seg = (tid >> 4) & 1, rA = tid >> 5;
  const bool actA = rA < nrows;
  const int nA     = slot*RPB + rA;            // node within batch
  const int nAs    = actA ? nA : 0;
  const int sbase  = bat * NNODE;
  const int hd   = tA >> 1;
  const int off8 = tA * 8;
  // layout F (GEMM): 16 col-groups (8 cols) x 32 rows on threads 0..511
  const int fgF = tid & 15, rsF = tid >> 4;    // rsF valid only for tid<512
  const bool actF = (tid < 512) && (rsF < nrows);
  const int rowF = row0 + rsF;

  // ---- one-time: per-block edge cache ----
  int s0r = 0, degr = 0;
  if (actA){ s0r = p.row_start[nA]; degr = p.row_start[nA+1] - s0r; }
  if ((tid & 31) == 0) degs_s[rA] = degr;
  __syncthreads();
  if (tid == 0){
    int o = 0;
    #pragma unroll
    for (int r = 0; r < RPB; ++r){ eoff[r] = o; o += degs_s[r]; }
    eoff[RPB] = o;
  }
  __syncthreads();
  const int* eptr;
  if (eoff[RPB] <= ECAP){
    const int eb = eoff[rA];
    for (int e = tA + 16*seg; e < degr; e += 32) esrc_l[eb + e] = p.edge_src[s0r + e];
    eptr = esrc_l + eb;
  } else {
    eptr = p.edge_src + s0r;   // statistically never; correctness fallback
  }

  // ---- one-time: per-thread epilogue constants (hot path only) ----
  float al8[8], ar8[8];
  {
    const int head = fgF >> 1, dbase = (fgF & 1) * 8;
    #pragma unroll
    for (int i=0;i<8;++i){
      al8[i] = p.a_l[head*DHEAD + dbase + i];
      ar8[i] = p.a_r[head*DHEAD + dbase + i];
    }
  }

  load_W<PTHREADS>(Wl, p.w_gat, tid);

  // ---- init: y0 = inputs[:,0]@w_in + b_in ----
  float yb8[8], ya8[8];
  {
    const float x0 = p.inputs[((bat*SEQL + 0)*NNODE + nAs)*2 + 0];
    const float x1 = p.inputs[((bat*SEQL + 0)*NNODE + nAs)*2 + 1];
    #pragma unroll
    for (int i=0;i<8;++i){
      int f = off8 + i;
      yb8[i] = x0*p.w_in[f] + x1*p.w_in[HID+f] + p.b_in[f];
    }
    if (seg == 0){
      *reinterpret_cast<float4*>(yt + rA*HID + off8)     = make_float4(yb8[0],yb8[1],yb8[2],yb8[3]);
      *reinterpret_cast<float4*>(yt + rA*HID + off8 + 4) = make_float4(yb8[4],yb8[5],yb8[6],yb8[7]);
    }
  }
  __syncthreads();     // yt, Wl, esrc_l staged
  if (tid < 512) gemm_epi8(Wl, yt, fgF, rsF, rowF, actF, p.hb0, p.elb0, er_l, al8, ar8);

  int step = 1;
  grid_bar(bar_b, NBLK_B * step); ++step;

  // per-segment edge range (contiguous halves)
  const int half0 = (degr + 1) >> 1;
  const int e_lo = seg ? half0 : 0;
  const int e_hi = seg ? degr  : half0;

  int rd = 0;
  for (int idx = 0; idx < SEQL; ++idx){
    for (int st = 0; st < 4; ++st){
      for (int j = 1; j <= 4; ++j){
        const float* __restrict__ h_rd  = rd ? p.hb1  : p.hb0;
        const float* __restrict__ el_rd = rd ? p.elb1 : p.elb0;
        float* __restrict__ h_wr  = rd ? p.hb0  : p.hb1;
        float* __restrict__ el_wr = rd ? p.elb0 : p.elb1;

        // ---- gather: softmax-weighted aggregation (layout A, 2 segs/row) ----
        float acc[8] = {0.f,0.f,0.f,0.f,0.f,0.f,0.f,0.f};
        float sum = 0.f;
        {
          const float erh = er_l[rA*NHEAD + hd];
          int e = e_lo;
          for (; e + 4 <= e_hi; e += 4){
            const int sA = sbase + eptr[e+0];
            const int sB = sbase + eptr[e+1];
            const int sC = sbase + eptr[e+2];
            const int sD = sbase + eptr[e+3];
            const float eA = el_rd[sA*NHEAD + hd];
            const float eB = el_rd[sB*NHEAD + hd];
            const float eC = el_rd[sC*NHEAD + hd];
            const float eD = el_rd[sD*NHEAD + hd];
            const float4 a0 = *reinterpret_cast<const float4*>(h_rd + sA*HID + off8);
            const float4 a1 = *reinterpret_cast<const float4*>(h_rd + sA*HID + off8 + 4);
            const float4 b0 = *reinterpret_cast<const float4*>(h_rd + sB*HID + off8);
            const float4 b1 = *reinterpret_cast<const float4*>(h_rd + sB*HID + off8 + 4);
            const float4 c0 = *reinterpret_cast<const float4*>(h_rd + sC*HID + off8);
            const float4 c1 = *reinterpret_cast<const float4*>(h_rd + sC*HID + off8 + 4);
            const float4 d0 = *reinterpret_cast<const float4*>(h_rd + sD*HID + off8);
            const float4 d1 = *reinterpret_cast<const float4*>(h_rd + sD*HID + off8 + 4);
            const float xA = eA + erh, xB = eB + erh, xC = eC + erh, xD = eD + erh;
            const float wA = __expf(fminf(fmaxf(xA, 0.2f*xA), 30.f));
            const float wB = __expf(fminf(fmaxf(xB, 0.2f*xB), 30.f));
            const float wC = __expf(fminf(fmaxf(xC, 0.2f*xC), 30.f));
            const float wD = __expf(fminf(fmaxf(xD, 0.2f*xD), 30.f));
            sum += (wA + wB) + (wC + wD);
            acc8(acc, wA, a0, a1); acc8(acc, wB, b0, b1);
            acc8(acc, wC, c0, c1); acc8(acc, wD, d0, d1);
          }
          for (; e < e_hi; ++e){
            const int sA = sbase + eptr[e];
            const float eA = el_rd[sA*NHEAD + hd];
            const float4 a0 = *reinterpret_cast<const float4*>(h_rd + sA*HID + off8);
            const float4 a1 = *reinterpret_cast<const float4*>(h_rd + sA*HID + off8 + 4);
            const float xA = eA + erh;
            const float wA = __expf(fminf(fmaxf(xA, 0.2f*xA), 30.f));
            sum += wA;
            acc8(acc, wA, a0, a1);
          }
        }
        // combine the two segments (lane ^ 16 = same row, other segment)
        sum += __shfl_xor(sum, 16);
        #pragma unroll
        for (int i=0;i<8;++i) acc[i] += __shfl_xor(acc[i], 16);
        const float inv = 1.f / (sum + 1e-16f);
        #pragma unroll
        for (int i=0;i<8;++i) acc[i] *= inv;

        // ---- RK4 register update (duplicated in both segs, identical) ----
        const bool is5 = (st == 3) && (j == 4);
        float nxt[8];
        if (j == 1){
          #pragma unroll
          for (int i=0;i<8;++i){ ya8[i] = fmaf(DT/6.f, acc[i], yb8[i]);
                                 nxt[i] = fmaf(0.5f*DT, acc[i], yb8[i]); }
        } else if (j == 2){
          #pragma unroll
          for (int i=0;i<8;++i){ ya8[i] = fmaf(DT/3.f, acc[i], ya8[i]);
                                 nxt[i] = fmaf(0.5f*DT, acc[i], yb8[i]); }
        } else if (j == 3){
          #pragma unroll
          for (int i=0;i<8;++i){ ya8[i] = fmaf(DT/3.f, acc[i], ya8[i]);
                                 nxt[i] = fmaf(DT, acc[i], yb8[i]); }
        } else {
          #pragma unroll
          for (int i=0;i<8;++i) nxt[i] = fmaf(DT/6.f, acc[i], ya8[i]);
          if (!is5){
            #pragma unroll
            for (int i=0;i<8;++i) yb8[i] = nxt[i];
          }
        }

        if (seg == 0){
          *reinterpret_cast<float4*>(yt + rA*HID + off8)     = make_float4(nxt[0],nxt[1],nxt[2],nxt[3]);
          *reinterpret_cast<float4*>(yt + rA*HID + off8 + 4) = make_float4(nxt[4],nxt[5],nxt[6],nxt[7]);
        }

        if (!is5){
          __syncthreads();
          if (tid < 512) gemm_epi8(Wl, yt, fgF, rsF, rowF, actF, h_wr, el_wr, er_l, al8, ar8);
          grid_bar(bar_b, NBLK_B * step); ++step;
          rd ^= 1;
          continue;
        }

        // ---- end of interval: optional GRU, LN, state handoff ----
        const bool last = (idx == SEQL-1);
        float z[8];
        if (idx > 0){
          load_W<PTHREADS>(Wl, p.w_W, tid);
          __syncthreads();                       // yt(y_new) + w_W ready
          if (tid < 512) gemm128_8(Wl, yt, fgF, rsF, z);   // z = y_new @ w_W
          __syncthreads();                       // gemm reads done
          {
            const float x0 = p.inputs[((bat*SEQL + idx)*NNODE + nAs)*2 + 0];
            const float x1 = p.inputs[((bat*SEQL + idx)*NNODE + nAs)*2 + 1];
            if (seg == 0){
              float hv[8];
              #pragma unroll
              for (int i=0;i<8;++i){
                int f = off8 + i;
                hv[i] = x0*p.w_in[f] + x1*p.w_in[HID+f] + p.b_in[f];
              }
              *reinterpret_cast<float4*>(yt + rA*HID + off8)     = make_float4(hv[0],hv[1],hv[2],hv[3]);
              *reinterpret_cast<float4*>(yt + rA*HID + off8 + 4) = make_float4(hv[4],hv[5],hv[6],hv[7]);
            }
          }
          load_W<PTHREADS>(Wl, p.w_U, tid);
          __syncthreads();
          if (tid < 512){
            float u[8];
            gemm128_8(Wl, yt, fgF, rsF, u);      // u = h_in @ w_U
            #pragma unroll
            for (int i=0;i<8;++i)
              z[i] = tanhf(z[i] + u[i] + p.b_W[fgF*8+i] + p.b_U[fgF*8+i]);
          }
        } else {
          __syncthreads();                       // yt(y_new) visible in F layout
          if (tid < 512){
            #pragma unroll
            for (int i=0;i<8;++i) z[i] = yt[rsF*HID + fgF*8 + i];
          }
        }
        // LayerNorm over 128 features (16 fg lanes x 8)
        if (tid < 512){
          float sv=0.f, qv=0.f;
          #pragma unroll
          for (int i=0;i<8;++i){ sv+=z[i]; qv+=z[i]*z[i]; }
          #pragma unroll
          for (int off=1; off<16; off<<=1){
            sv += __shfl_xor(sv, off); qv += __shfl_xor(qv, off);
          }
          float mu = sv*(1.f/HID);
          float r  = rsqrtf(qv*(1.f/HID) - mu*mu + 1e-5f);
          #pragma unroll
          for (int i=0;i<8;++i) z[i] = (z[i]-mu)*r;
        }
        __syncthreads();                         // all yt readers done
        if (tid < 512){
          *reinterpret_cast<float4*>(yt + rsF*HID + fgF*8)     = make_float4(z[0],z[1],z[2],z[3]);
          *reinterpret_cast<float4*>(yt + rsF*HID + fgF*8 + 4) = make_float4(z[4],z[5],z[6],z[7]);
          if (last && actF){
            *reinterpret_cast<float4*>(p.y_out + rowF*HID + fgF*8)     = make_float4(z[0],z[1],z[2],z[3]);
            *reinterpret_cast<float4*>(p.y_out + rowF*HID + fgF*8 + 4) = make_float4(z[4],z[5],z[6],z[7]);
          }
        }
        if (!last){
          if (idx > 0) load_W<PTHREADS>(Wl, p.w_gat, tid);  // restore resident w_gat
          __syncthreads();
          #pragma unroll
          for (int i=0;i<8;++i) yb8[i] = yt[rA*HID + off8 + i];  // new y state
          if (tid < 512) gemm_epi8(Wl, yt, fgF, rsF, rowF, actF, h_wr, el_wr, er_l, al8, ar8);
          grid_bar(bar_b, NBLK_B * step); ++step;
          rd ^= 1;
        }
        // last: no more barriers; blocks exit; kernel boundary flushes caches
      }
    }
  }
}

// out = tanh(ret @ w_o1 + b_o1) @ w_o2 + b_o2, fp32 output
__global__ void __launch_bounds__(256, 2) out_kernel(
    const float* __restrict__ y_base,
    const float* __restrict__ w_o1, const float* __restrict__ b_o1,
    const float* __restrict__ w_o2, const float* __restrict__ b_o2,
    float* __restrict__ out)
{
  __shared__ float Wl[HID*HID];
  __shared__ float yt[ORPB*HID];
  const int tid = threadIdx.x;
  const int row0 = blockIdx.x * ORPB;
  const int rA = tid >> 4, tA = tid & 15;
  const int rowA = row0 + rA;
  {
    float4 v0 = *reinterpret_cast<const float4*>(y_base + rowA*HID + tA*8);
    float4 v1 = *reinterpret_cast<const float4*>(y_base + rowA*HID + tA*8 + 4);
    *reinterpret_cast<float4*>(yt + rA*HID + tA*8)     = v0;
    *reinterpret_cast<float4*>(yt + rA*HID + tA*8 + 4) = v1;
  }
  load_W<256>(Wl, w_o1, tid);
  __syncthreads();
  const int fg = tid & 31, rs = tid >> 5;
  float t0[4], t1[4];
  gemm128<8>(Wl, yt, fg, rs, t0, t1);
  #pragma unroll
  for (int i=0;i<4;++i){
    float bb = b_o1[fg*4+i];
    t0[i] = tanhf(t0[i] + bb);
    t1[i] = tanhf(t1[i] + bb);
  }
  __syncthreads();
  *reinterpret_cast<float4*>(yt + rs*HID + fg*4)     = make_float4(t0[0],t0[1],t0[2],t0[3]);
  *reinterpret_cast<float4*>(yt + (rs+8)*HID + fg*4) = make_float4(t1[0],t1[1],t1[2],t1[3]);
  load_W<256>(Wl, w_o2, tid);
  __syncthreads();
  float o0[4], o1[4];
  gemm128<8>(Wl, yt, fg, rs, o0, o1);
  const int rowF0 = row0 + rs, rowF1 = row0 + rs + 8;
  *reinterpret_cast<float4*>(out + rowF0*HID + fg*4) =
      make_float4(o0[0]+b_o2[fg*4+0], o0[1]+b_o2[fg*4+1], o0[2]+b_o2[fg*4+2], o0[3]+b_o2[fg*4+3]);
  *reinterpret_cast<float4*>(out + rowF1*HID + fg*4) =
      make_float4(o1[0]+b_o2[fg*4+0], o1[1]+b_o2[fg*4+1], o1[2]+b_o2[fg*4+2], o1[3]+b_o2[fg*4+3]);
}

extern "C" void kernel_launch(void* const* d_in, const int* in_sizes, int n_in,
                              void* d_out, int out_size, void* d_ws, size_t ws_size,
                              hipStream_t stream)
{
  const float* inputs = (const float*)d_in[0];
  const int* src      = (const int*)d_in[1];
  const int* dst      = (const int*)d_in[2];
  const float* w_in   = (const float*)d_in[3];
  const float* b_in   = (const float*)d_in[4];
  const float* w_gat  = (const float*)d_in[5];
  const float* a_l    = (const float*)d_in[6];
  const float* a_r    = (const float*)d_in[7];
  const float* w_W    = (const float*)d_in[8];
  const float* b_W    = (const float*)d_in[9];
  const float* w_U    = (const float*)d_in[10];
  const float* b_U    = (const float*)d_in[11];
  const float* w_o1   = (const float*)d_in[12];
  const float* b_o1   = (const float*)d_in[13];
  const float* w_o2   = (const float*)d_in[14];
  const float* b_o2   = (const float*)d_in[15];

  float* F = reinterpret_cast<float*>(d_ws);
  const size_t RH = (size_t)NROWS * HID;    // 1,024,000
  const size_t RE = (size_t)NROWS * NHEAD;  // 64,000
  size_t need = (3*RH + 2*RE)*sizeof(float)
              + (size_t)(1024 + NEDGE + NBATCH*BARSTRIDE)*sizeof(int);
  if (ws_size < need) return;

  float* hb0   = F;
  float* hb1   = F + RH;
  float* y_out = F + 2*RH;
  float* elb0  = F + 3*RH;
  float* elb1  = elb0 + RE;
  int* I = reinterpret_cast<int*>(elb1 + RE);
  int* row_start = I;
  int* edge_src  = I + 1024;
  int* bar       = I + 1024 + NEDGE;

  csr_kernel<<<1, 1024, 0, stream>>>(src, dst, row_start, edge_src, bar);

  PArgs pa;
  pa.hb0 = hb0; pa.elb0 = elb0; pa.hb1 = hb1; pa.elb1 = elb1; pa.y_out = y_out;
  pa.row_start = row_start; pa.edge_src = edge_src;
  pa.w_gat = w_gat; pa.a_l = a_l; pa.a_r = a_r;
  pa.inputs = inputs; pa.w_in = w_in; pa.b_in = b_in;
  pa.w_W = w_W; pa.b_W = b_W; pa.w_U = w_U; pa.b_U = b_U;
  pa.bar = bar;

  persist<<<NBLK_P, PTHREADS, 0, stream>>>(pa);

  out_kernel<<<NBLK_O, 256, 0, stream>>>(y_out, w_o1, b_o1, w_o2, b_o2, (float*)d_out);
}

// Round 8
// 4091.107 us; speedup vs baseline: 1.7783x; 1.3988x over previous
//
#include <hip/hip_runtime.h>

#define NNODE 1000
#define NBATCH 8
#define SEQL 12
#define NHEAD 8
#define DHEAD 16
#define HID 128
#define NEDGE 16000
#define NROWS (NBATCH*NNODE)   // 8000
#define RPB 32                 // rows per persistent block
#define NBLK_P 256             // 8 batch-groups x 32 slots; 1 block/CU
#define NBLK_B 32              // blocks per batch = barrier width
#define BARSTRIDE 64           // ints between per-batch counters (256 B)
#define PTHREADS 1024
#define ORPB 16
#define NBLK_O (NROWS/ORPB)    // 500
#define DT 0.25f
#define ECAP 768               // LDS edge cache (block mean 512)
#define SPIN_LIMIT 100000ULL   // 1 ms escape hatch (finite wrong-run, not hang)

// ---- agent-scope (MALL point-of-coherence) data access helpers ----
// On gfx950 agent-scope atomics bypass the non-coherent per-XCD L2, so
// cross-block h/el traffic never needs wbl2/invl2 cache walks.
__device__ __forceinline__ void st_agent_f2(float* p, float a, float b){
  float2 t = make_float2(a, b);
  unsigned long long u;
  __builtin_memcpy(&u, &t, 8);
  __hip_atomic_store(reinterpret_cast<unsigned long long*>(p), u,
                     __ATOMIC_RELAXED, __HIP_MEMORY_SCOPE_AGENT);
}
__device__ __forceinline__ float2 ld_agent_f2(const float* p){
  unsigned long long u =
    __hip_atomic_load(reinterpret_cast<const unsigned long long*>(p),
                      __ATOMIC_RELAXED, __HIP_MEMORY_SCOPE_AGENT);
  float2 t;
  __builtin_memcpy(&t, &u, 8);
  return t;
}
__device__ __forceinline__ float4 ld_agent_f4(const float* p){
  float2 a = ld_agent_f2(p);
  float2 b = ld_agent_f2(p + 2);
  return make_float4(a.x, a.y, b.x, b.y);
}
__device__ __forceinline__ void st_agent_f(float* p, float v){
  __hip_atomic_store(p, v, __ATOMIC_RELAXED, __HIP_MEMORY_SCOPE_AGENT);
}
__device__ __forceinline__ float ld_agent_f(const float* p){
  return __hip_atomic_load(p, __ATOMIC_RELAXED, __HIP_MEMORY_SCOPE_AGENT);
}

// ---- per-batch barrier WITHOUT cache-maintenance fences ----
// All shared data ops are agent-scope atomics (already coherent at MALL), so
// release ordering on the fetch_add (s_waitcnt vmcnt(0) before it) is the
// only ordering needed; the spin load is relaxed; __syncthreads publishes to
// the block. No __threadfence -> no wbl2/invl2 walks per stage.
__device__ __forceinline__ void grid_bar(int* bar, int target){
  __syncthreads();
  if (threadIdx.x == 0){
    __hip_atomic_fetch_add(bar, 1, __ATOMIC_RELEASE, __HIP_MEMORY_SCOPE_AGENT);
    unsigned long long t0 = __builtin_amdgcn_s_memrealtime();
    while (__hip_atomic_load(bar, __ATOMIC_RELAXED, __HIP_MEMORY_SCOPE_AGENT) < target){
      __builtin_amdgcn_s_sleep(2);
      if (__builtin_amdgcn_s_memrealtime() - t0 > SPIN_LIMIT) break;
    }
  }
  __syncthreads();
}

// copy a 128x128 fp32 matrix global->LDS, NT threads
template<int NT>
__device__ __forceinline__ void load_W(float* Wl, const float* g, int tid){
  #pragma unroll
  for (int c = 0; c < (HID*HID/4)/NT; ++c){
    int e = (c*NT + tid)*4;
    *reinterpret_cast<float4*>(Wl + e) = *reinterpret_cast<const float4*>(g + e);
  }
}

// one row, 4 cols: o[j] = sum_k yt[rs][k]*Wl[k][fg*4+j]   (round-6 low-conflict layout)
__device__ __forceinline__ void gemm128_1(const float* Wl, const float* yt, int fg, int rs,
                                          float o[4]){
  float a0[4]={0.f,0.f,0.f,0.f};
  #pragma unroll 4
  for (int k=0;k<HID;k+=4){
    float4 ya = *reinterpret_cast<const float4*>(yt + rs*HID + k);
    #pragma unroll
    for (int kk=0;kk<4;++kk){
      const float* wr = Wl + (k+kk)*HID + fg*4;
      float av = (&ya.x)[kk];
      #pragma unroll
      for (int i=0;i<4;++i) a0[i] = fmaf(wr[i], av, a0[i]);
    }
  }
  #pragma unroll
  for (int i=0;i<4;++i) o[i]=a0[i];
}

// two rows (rs, rs+RSTEP), 4 cols — used by out_kernel
template<int RSTEP>
__device__ __forceinline__ void gemm128(const float* Wl, const float* yt, int fg, int rs,
                                        float o0[4], float o1[4]){
  float a0[4]={0.f,0.f,0.f,0.f}, a1[4]={0.f,0.f,0.f,0.f};
  #pragma unroll 4
  for (int k=0;k<HID;k+=4){
    float4 ya = *reinterpret_cast<const float4*>(yt + rs*HID + k);
    float4 yb = *reinterpret_cast<const float4*>(yt + (rs+RSTEP)*HID + k);
    #pragma unroll
    for (int kk=0;kk<4;++kk){
      const float* wr = Wl + (k+kk)*HID + fg*4;
      float av = (&ya.x)[kk];
      float bv = (&yb.x)[kk];
      #pragma unroll
      for (int i=0;i<4;++i){
        float w = wr[i];
        a0[i] = fmaf(w, av, a0[i]);
        a1[i] = fmaf(w, bv, a1[i]);
      }
    }
  }
  #pragma unroll
  for (int i=0;i<4;++i){ o0[i]=a0[i]; o1[i]=a1[i]; }
}

// acc[0..7] += wt * {v0.xyzw, v1.xyzw}
__device__ __forceinline__ void acc8(float acc[8], float wt, const float4& v0, const float4& v1){
  acc[0]=fmaf(wt,v0.x,acc[0]); acc[1]=fmaf(wt,v0.y,acc[1]);
  acc[2]=fmaf(wt,v0.z,acc[2]); acc[3]=fmaf(wt,v0.w,acc[3]);
  acc[4]=fmaf(wt,v1.x,acc[4]); acc[5]=fmaf(wt,v1.y,acc[5]);
  acc[6]=fmaf(wt,v1.z,acc[6]); acc[7]=fmaf(wt,v1.w,acc[7]);
}

// h = yt[rs] @ Wl (1 row x 4 cols/thread, 1024 threads); h + el via agent
// stores, own-row er to LDS.
__device__ __forceinline__ void gemm_epi(const float* Wl, const float* yt,
    int fg, int rs, int rowF, bool actF,
    float* __restrict__ h_wr, float* __restrict__ el_wr, float* er_l,
    const float al4[4], const float ar4[4])
{
  float o[4];
  gemm128_1(Wl, yt, fg, rs, o);
  if (actF){
    st_agent_f2(h_wr + rowF*HID + fg*4,     o[0], o[1]);
    st_agent_f2(h_wr + rowF*HID + fg*4 + 2, o[2], o[3]);
  }
  const int hd2 = fg >> 2;
  float el=0.f, er=0.f;
  #pragma unroll
  for (int i=0;i<4;++i){
    el = fmaf(o[i], al4[i], el); er = fmaf(o[i], ar4[i], er);
  }
  el += __shfl_xor(el,1); el += __shfl_xor(el,2);
  er += __shfl_xor(er,1); er += __shfl_xor(er,2);
  if ((fg & 3) == 0 && actF){
    st_agent_f(el_wr + rowF*NHEAD + hd2, el);
    er_l[rs*NHEAD + hd2] = er;
  }
}

// Build CSR (edges sorted by dst); zero the 8 per-batch barrier counters.
__global__ void csr_kernel(const int* __restrict__ src, const int* __restrict__ dst,
                           int* __restrict__ row_start, int* __restrict__ edge_src,
                           int* __restrict__ bar){
  __shared__ int cnt[1024];
  __shared__ int scanb[1024];
  __shared__ int cur[1024];
  int tid = threadIdx.x;
  if (tid < NBATCH*BARSTRIDE) bar[tid] = 0;
  cnt[tid] = 0;
  __syncthreads();
  for (int e = tid; e < NEDGE; e += 1024) atomicAdd(&cnt[dst[e]], 1);
  __syncthreads();
  int v = cnt[tid];
  scanb[tid] = v;
  __syncthreads();
  for (int off=1; off<1024; off<<=1){
    int t = (tid >= off) ? scanb[tid-off] : 0;
    __syncthreads();
    scanb[tid] += t;
    __syncthreads();
  }
  int incl = scanb[tid];
  if (tid < NNODE){ cur[tid] = incl - v; row_start[tid+1] = incl; }
  if (tid == 0) row_start[0] = 0;
  __syncthreads();
  for (int e = tid; e < NEDGE; e += 1024){
    int d = dst[e];
    int pos = atomicAdd(&cur[d], 1);
    edge_src[pos] = src[e];
  }
}

struct PArgs {
  float* hb0; float* elb0; float* hb1; float* elb1; float* y_out;
  const int* row_start; const int* edge_src;
  const float* w_gat; const float* a_l; const float* a_r;
  const float* inputs; const float* w_in; const float* b_in;
  const float* w_W; const float* b_W; const float* w_U; const float* b_U;
  int* bar;
};

__global__ void __launch_bounds__(PTHREADS, 4) persist(PArgs p)
{
  __shared__ float Wl[HID*HID];      // 64 KB — w_gat resident except around GRU
  __shared__ float yt[RPB*HID];      // 16 KB
  __shared__ int   esrc_l[ECAP];     // 3 KB
  __shared__ int   eoff[RPB+1];
  __shared__ int   degs_s[RPB];
  __shared__ float er_l[RPB*NHEAD];  // ~86 KB total -> 1 block/CU, 16 waves

  const int tid  = threadIdx.x;
  // batch grouping doubles as XCD-locality heuristic (blockIdx%8 -> XCD)
  const int bat   = blockIdx.x & 7;            // batch index
  const int slot  = blockIdx.x >> 3;           // 0..31
  const int row0  = bat * NNODE + slot * RPB;
  const int nrows = (slot == 31) ? (NNODE - 31*RPB) : RPB;   // 8 or 32
  int* const bar_b = p.bar + bat * BARSTRIDE;
  // layout A (gather): 16 threads x 2 edge-segments per row, 32 rows
  const int tA = tid & 15, seg = (tid >> 4) & 1, rA = tid >> 5;
  const bool actA = rA < nrows;
  const int nA     = slot*RPB + rA;            // node within batch
  const int nAs    = actA ? nA : 0;
  const int sbase  = bat * NNODE;
  const int hd   = tA >> 1;
  const int off8 = tA * 8;
  // layout F (GEMM): 32 col-groups (4 cols) x 32 rows, all 1024 threads
  const int fg = tid & 31, rs = tid >> 5;
  const bool actF = rs < nrows;
  const int rowF = row0 + rs;
  const int hd2 = fg >> 2, db = (fg & 3) * 4;

  // ---- one-time: per-block edge cache ----
  int s0r = 0, degr = 0;
  if (actA){ s0r = p.row_start[nA]; degr = p.row_start[nA+1] - s0r; }
  if ((tid & 31) == 0) degs_s[rA] = degr;
  __syncthreads();
  if (tid == 0){
    int o = 0;
    #pragma unroll
    for (int r = 0; r < RPB; ++r){ eoff[r] = o; o += degs_s[r]; }
    eoff[RPB] = o;
  }
  __syncthreads();
  const int* eptr;
  if (eoff[RPB] <= ECAP){
    const int eb = eoff[rA];
    for (int e = tA + 16*seg; e < degr; e += 32) esrc_l[eb + e] = p.edge_src[s0r + e];
    eptr = esrc_l + eb;
  } else {
    eptr = p.edge_src + s0r;   // statistically never; correctness fallback
  }

  // ---- one-time: per-thread epilogue constants ----
  float al4[4], ar4[4];
  #pragma unroll
  for (int i=0;i<4;++i){
    al4[i] = p.a_l[hd2*DHEAD + db + i];
    ar4[i] = p.a_r[hd2*DHEAD + db + i];
  }

  load_W<PTHREADS>(Wl, p.w_gat, tid);

  // ---- init: y0 = inputs[:,0]@w_in + b_in ----
  float yb8[8], ya8[8];
  {
    const float x0 = p.inputs[((bat*SEQL + 0)*NNODE + nAs)*2 + 0];
    const float x1 = p.inputs[((bat*SEQL + 0)*NNODE + nAs)*2 + 1];
    #pragma unroll
    for (int i=0;i<8;++i){
      int f = off8 + i;
      yb8[i] = x0*p.w_in[f] + x1*p.w_in[HID+f] + p.b_in[f];
    }
    if (seg == 0){
      *reinterpret_cast<float4*>(yt + rA*HID + off8)     = make_float4(yb8[0],yb8[1],yb8[2],yb8[3]);
      *reinterpret_cast<float4*>(yt + rA*HID + off8 + 4) = make_float4(yb8[4],yb8[5],yb8[6],yb8[7]);
    }
  }
  __syncthreads();     // yt, Wl, esrc_l staged
  gemm_epi(Wl, yt, fg, rs, rowF, actF, p.hb0, p.elb0, er_l, al4, ar4);

  int step = 1;
  grid_bar(bar_b, NBLK_B * step); ++step;

  // per-segment edge range (contiguous halves)
  const int half0 = (degr + 1) >> 1;
  const int e_lo = seg ? half0 : 0;
  const int e_hi = seg ? degr  : half0;

  int rd = 0;
  for (int idx = 0; idx < SEQL; ++idx){
    for (int st = 0; st < 4; ++st){
      for (int j = 1; j <= 4; ++j){
        const float* __restrict__ h_rd  = rd ? p.hb1  : p.hb0;
        const float* __restrict__ el_rd = rd ? p.elb1 : p.elb0;
        float* __restrict__ h_wr  = rd ? p.hb0  : p.hb1;
        float* __restrict__ el_wr = rd ? p.elb0 : p.elb1;

        // ---- gather: softmax-weighted aggregation (layout A, 2 segs/row) ----
        float acc[8] = {0.f,0.f,0.f,0.f,0.f,0.f,0.f,0.f};
        float sum = 0.f;
        {
          const float erh = er_l[rA*NHEAD + hd];
          int e = e_lo;
          for (; e + 4 <= e_hi; e += 4){
            const int sA = sbase + eptr[e+0];
            const int sB = sbase + eptr[e+1];
            const int sC = sbase + eptr[e+2];
            const int sD = sbase + eptr[e+3];
            const float eA = ld_agent_f(el_rd + sA*NHEAD + hd);
            const float eB = ld_agent_f(el_rd + sB*NHEAD + hd);
            const float eC = ld_agent_f(el_rd + sC*NHEAD + hd);
            const float eD = ld_agent_f(el_rd + sD*NHEAD + hd);
            const float4 a0 = ld_agent_f4(h_rd + sA*HID + off8);
            const float4 a1 = ld_agent_f4(h_rd + sA*HID + off8 + 4);
            const float4 b0 = ld_agent_f4(h_rd + sB*HID + off8);
            const float4 b1 = ld_agent_f4(h_rd + sB*HID + off8 + 4);
            const float4 c0 = ld_agent_f4(h_rd + sC*HID + off8);
            const float4 c1 = ld_agent_f4(h_rd + sC*HID + off8 + 4);
            const float4 d0 = ld_agent_f4(h_rd + sD*HID + off8);
            const float4 d1 = ld_agent_f4(h_rd + sD*HID + off8 + 4);
            const float xA = eA + erh, xB = eB + erh, xC = eC + erh, xD = eD + erh;
            const float wA = __expf(fminf(fmaxf(xA, 0.2f*xA), 30.f));
            const float wB = __expf(fminf(fmaxf(xB, 0.2f*xB), 30.f));
            const float wC = __expf(fminf(fmaxf(xC, 0.2f*xC), 30.f));
            const float wD = __expf(fminf(fmaxf(xD, 0.2f*xD), 30.f));
            sum += (wA + wB) + (wC + wD);
            acc8(acc, wA, a0, a1); acc8(acc, wB, b0, b1);
            acc8(acc, wC, c0, c1); acc8(acc, wD, d0, d1);
          }
          for (; e < e_hi; ++e){
            const int sA = sbase + eptr[e];
            const float eA = ld_agent_f(el_rd + sA*NHEAD + hd);
            const float4 a0 = ld_agent_f4(h_rd + sA*HID + off8);
            const float4 a1 = ld_agent_f4(h_rd + sA*HID + off8 + 4);
            const float xA = eA + erh;
            const float wA = __expf(fminf(fmaxf(xA, 0.2f*xA), 30.f));
            sum += wA;
            acc8(acc, wA, a0, a1);
          }
        }
        // combine the two segments (lane ^ 16 = same row, other segment)
        sum += __shfl_xor(sum, 16);
        #pragma unroll
        for (int i=0;i<8;++i) acc[i] += __shfl_xor(acc[i], 16);
        const float inv = 1.f / (sum + 1e-16f);
        #pragma unroll
        for (int i=0;i<8;++i) acc[i] *= inv;

        // ---- RK4 register update (duplicated in both segs, identical) ----
        const bool is5 = (st == 3) && (j == 4);
        float nxt[8];
        if (j == 1){
          #pragma unroll
          for (int i=0;i<8;++i){ ya8[i] = fmaf(DT/6.f, acc[i], yb8[i]);
                                 nxt[i] = fmaf(0.5f*DT, acc[i], yb8[i]); }
        } else if (j == 2){
          #pragma unroll
          for (int i=0;i<8;++i){ ya8[i] = fmaf(DT/3.f, acc[i], ya8[i]);
                                 nxt[i] = fmaf(0.5f*DT, acc[i], yb8[i]); }
        } else if (j == 3){
          #pragma unroll
          for (int i=0;i<8;++i){ ya8[i] = fmaf(DT/3.f, acc[i], ya8[i]);
                                 nxt[i] = fmaf(DT, acc[i], yb8[i]); }
        } else {
          #pragma unroll
          for (int i=0;i<8;++i) nxt[i] = fmaf(DT/6.f, acc[i], ya8[i]);
          if (!is5){
            #pragma unroll
            for (int i=0;i<8;++i) yb8[i] = nxt[i];
          }
        }

        if (seg == 0){
          *reinterpret_cast<float4*>(yt + rA*HID + off8)     = make_float4(nxt[0],nxt[1],nxt[2],nxt[3]);
          *reinterpret_cast<float4*>(yt + rA*HID + off8 + 4) = make_float4(nxt[4],nxt[5],nxt[6],nxt[7]);
        }

        if (!is5){
          __syncthreads();
          gemm_epi(Wl, yt, fg, rs, rowF, actF, h_wr, el_wr, er_l, al4, ar4);
          grid_bar(bar_b, NBLK_B * step); ++step;
          rd ^= 1;
          continue;
        }

        // ---- end of interval: optional GRU, LN, state handoff ----
        const bool last = (idx == SEQL-1);
        float z[4];
        if (idx > 0){
          load_W<PTHREADS>(Wl, p.w_W, tid);
          __syncthreads();                       // yt(y_new) + w_W ready
          gemm128_1(Wl, yt, fg, rs, z);          // z = y_new @ w_W
          __syncthreads();                       // gemm reads done
          {
            const float x0 = p.inputs[((bat*SEQL + idx)*NNODE + nAs)*2 + 0];
            const float x1 = p.inputs[((bat*SEQL + idx)*NNODE + nAs)*2 + 1];
            if (seg == 0){
              float hv[8];
              #pragma unroll
              for (int i=0;i<8;++i){
                int f = off8 + i;
                hv[i] = x0*p.w_in[f] + x1*p.w_in[HID+f] + p.b_in[f];
              }
              *reinterpret_cast<float4*>(yt + rA*HID + off8)     = make_float4(hv[0],hv[1],hv[2],hv[3]);
              *reinterpret_cast<float4*>(yt + rA*HID + off8 + 4) = make_float4(hv[4],hv[5],hv[6],hv[7]);
            }
          }
          load_W<PTHREADS>(Wl, p.w_U, tid);
          __syncthreads();
          float u[4];
          gemm128_1(Wl, yt, fg, rs, u);          // u = h_in @ w_U
          #pragma unroll
          for (int i=0;i<4;++i)
            z[i] = tanhf(z[i] + u[i] + p.b_W[fg*4+i] + p.b_U[fg*4+i]);
        } else {
          __syncthreads();                       // yt(y_new) visible in F layout
          #pragma unroll
          for (int i=0;i<4;++i) z[i] = yt[rs*HID + fg*4 + i];
        }
        // LayerNorm over 128 features (32 fg lanes)
        {
          float sv=0.f, qv=0.f;
          #pragma unroll
          for (int i=0;i<4;++i){ sv+=z[i]; qv+=z[i]*z[i]; }
          #pragma unroll
          for (int off=1; off<32; off<<=1){
            sv += __shfl_xor(sv, off); qv += __shfl_xor(qv, off);
          }
          float mu = sv*(1.f/HID);
          float r  = rsqrtf(qv*(1.f/HID) - mu*mu + 1e-5f);
          #pragma unroll
          for (int i=0;i<4;++i) z[i] = (z[i]-mu)*r;
        }
        __syncthreads();                         // all yt readers done
        *reinterpret_cast<float4*>(yt + rs*HID + fg*4) = make_float4(z[0],z[1],z[2],z[3]);
        if (last && actF)
          *reinterpret_cast<float4*>(p.y_out + rowF*HID + fg*4) = make_float4(z[0],z[1],z[2],z[3]);
        if (!last){
          if (idx > 0) load_W<PTHREADS>(Wl, p.w_gat, tid);  // restore resident w_gat
          __syncthreads();
          #pragma unroll
          for (int i=0;i<8;++i) yb8[i] = yt[rA*HID + off8 + i];  // new y state
          gemm_epi(Wl, yt, fg, rs, rowF, actF, h_wr, el_wr, er_l, al4, ar4);
          grid_bar(bar_b, NBLK_B * step); ++step;
          rd ^= 1;
        }
        // last: no more barriers; blocks exit; kernel boundary flushes caches
      }
    }
  }
}

// out = tanh(ret @ w_o1 + b_o1) @ w_o2 + b_o2, fp32 output
__global__ void __launch_bounds__(256, 2) out_kernel(
    const float* __restrict__ y_base,
    const float* __restrict__ w_o1, const float* __restrict__ b_o1,
    const float* __restrict__ w_o2, const float* __restrict__ b_o2,
    float* __restrict__ out)
{
  __shared__ float Wl[HID*HID];
  __shared__ float yt[ORPB*HID];
  const int tid = threadIdx.x;
  const int row0 = blockIdx.x * ORPB;
  const int rA = tid >> 4, tA = tid & 15;
  const int rowA = row0 + rA;
  {
    float4 v0 = *reinterpret_cast<const float4*>(y_base + rowA*HID + tA*8);
    float4 v1 = *reinterpret_cast<const float4*>(y_base + rowA*HID + tA*8 + 4);
    *reinterpret_cast<float4*>(yt + rA*HID + tA*8)     = v0;
    *reinterpret_cast<float4*>(yt + rA*HID + tA*8 + 4) = v1;
  }
  load_W<256>(Wl, w_o1, tid);
  __syncthreads();
  const int fg = tid & 31, rs = tid >> 5;
  float t0[4], t1[4];
  gemm128<8>(Wl, yt, fg, rs, t0, t1);
  #pragma unroll
  for (int i=0;i<4;++i){
    float bb = b_o1[fg*4+i];
    t0[i] = tanhf(t0[i] + bb);
    t1[i] = tanhf(t1[i] + bb);
  }
  __syncthreads();
  *reinterpret_cast<float4*>(yt + rs*HID + fg*4)     = make_float4(t0[0],t0[1],t0[2],t0[3]);
  *reinterpret_cast<float4*>(yt + (rs+8)*HID + fg*4) = make_float4(t1[0],t1[1],t1[2],t1[3]);
  load_W<256>(Wl, w_o2, tid);
  __syncthreads();
  float o0[4], o1[4];
  gemm128<8>(Wl, yt, fg, rs, o0, o1);
  const int rowF0 = row0 + rs, rowF1 = row0 + rs + 8;
  *reinterpret_cast<float4*>(out + rowF0*HID + fg*4) =
      make_float4(o0[0]+b_o2[fg*4+0], o0[1]+b_o2[fg*4+1], o0[2]+b_o2[fg*4+2], o0[3]+b_o2[fg*4+3]);
  *reinterpret_cast<float4*>(out + rowF1*HID + fg*4) =
      make_float4(o1[0]+b_o2[fg*4+0], o1[1]+b_o2[fg*4+1], o1[2]+b_o2[fg*4+2], o1[3]+b_o2[fg*4+3]);
}

extern "C" void kernel_launch(void* const* d_in, const int* in_sizes, int n_in,
                              void* d_out, int out_size, void* d_ws, size_t ws_size,
                              hipStream_t stream)
{
  const float* inputs = (const float*)d_in[0];
  const int* src      = (const int*)d_in[1];
  const int* dst      = (const int*)d_in[2];
  const float* w_in   = (const float*)d_in[3];
  const float* b_in   = (const float*)d_in[4];
  const float* w_gat  = (const float*)d_in[5];
  const float* a_l    = (const float*)d_in[6];
  const float* a_r    = (const float*)d_in[7];
  const float* w_W    = (const float*)d_in[8];
  const float* b_W    = (const float*)d_in[9];
  const float* w_U    = (const float*)d_in[10];
  const float* b_U    = (const float*)d_in[11];
  const float* w_o1   = (const float*)d_in[12];
  const float* b_o1   = (const float*)d_in[13];
  const float* w_o2   = (const float*)d_in[14];
  const float* b_o2   = (const float*)d_in[15];

  float* F = reinterpret_cast<float*>(d_ws);
  const size_t RH = (size_t)NROWS * HID;    // 1,024,000
  const size_t RE = (size_t)NROWS * NHEAD;  // 64,000
  size_t need = (3*RH + 2*RE)*sizeof(float)
              + (size_t)(1024 + NEDGE + NBATCH*BARSTRIDE)*sizeof(int);
  if (ws_size < need) return;

  float* hb0   = F;
  float* hb1   = F + RH;
  float* y_out = F + 2*RH;
  float* elb0  = F + 3*RH;
  float* elb1  = elb0 + RE;
  int* I = reinterpret_cast<int*>(elb1 + RE);
  int* row_start = I;
  int* edge_src  = I + 1024;
  int* bar       = I + 1024 + NEDGE;

  csr_kernel<<<1, 1024, 0, stream>>>(src, dst, row_start, edge_src, bar);

  PArgs pa;
  pa.hb0 = hb0; pa.elb0 = elb0; pa.hb1 = hb1; pa.elb1 = elb1; pa.y_out = y_out;
  pa.row_start = row_start; pa.edge_src = edge_src;
  pa.w_gat = w_gat; pa.a_l = a_l; pa.a_r = a_r;
  pa.inputs = inputs; pa.w_in = w_in; pa.b_in = b_in;
  pa.w_W = w_W; pa.b_W = b_W; pa.w_U = w_U; pa.b_U = b_U;
  pa.bar = bar;

  persist<<<NBLK_P, PTHREADS, 0, stream>>>(pa);

  out_kernel<<<NBLK_O, 256, 0, stream>>>(y_out, w_o1, b_o1, w_o2, b_o2, (float*)d_out);
}

// Round 9
// 2877.242 us; speedup vs baseline: 2.5285x; 1.4219x over previous
//
#include <hip/hip_runtime.h>

#define NNODE 1000
#define NBATCH 8
#define SEQL 12
#define NHEAD 8
#define DHEAD 16
#define HID 128
#define NEDGE 16000
#define NROWS (NBATCH*NNODE)   // 8000
#define RPB 32                 // rows per persistent block
#define NBLK_P 256             // 8 batch-groups x 32 slots; 1 block/CU
#define NBLK_B 32              // blocks per batch = barrier width
#define BARSTRIDE 64           // ints between per-batch counters (256 B)
#define PTHREADS 1024
#define ORPB 16
#define NBLK_O (NROWS/ORPB)    // 500
#define DT 0.25f
#define ECAP 768               // LDS edge cache (block mean 512)
#define SPIN_LIMIT 100000ULL   // 1 ms escape hatch (finite wrong-run, not hang)

typedef unsigned short u16;
typedef unsigned int   u32;
typedef unsigned long long u64;

__device__ __forceinline__ u16 f2bf(float f){
  u32 x = __float_as_uint(f);
  return (u16)((x + 0x7fffu + ((x>>16)&1u)) >> 16);
}
__device__ __forceinline__ float bf2f(u16 u){ return __uint_as_float(((u32)u)<<16); }

// ---- agent-scope (MALL point-of-coherence) h exchange ----
// sc1 atomics bypass the non-coherent per-XCD L2; no wbl2/invl2 needed.
__device__ __forceinline__ u64 ld_agent_u64(const u16* p){
  return __hip_atomic_load(reinterpret_cast<const u64*>(p),
                           __ATOMIC_RELAXED, __HIP_MEMORY_SCOPE_AGENT);
}
__device__ __forceinline__ void st_agent_u64(u16* p, u64 v){
  __hip_atomic_store(reinterpret_cast<u64*>(p), v,
                     __ATOMIC_RELAXED, __HIP_MEMORY_SCOPE_AGENT);
}

// ---- per-batch barrier: release fetch_add orders prior sc1 stores; no fences ----
__device__ __forceinline__ void grid_bar(int* bar, int target){
  __syncthreads();
  if (threadIdx.x == 0){
    __hip_atomic_fetch_add(bar, 1, __ATOMIC_RELEASE, __HIP_MEMORY_SCOPE_AGENT);
    unsigned long long t0 = __builtin_amdgcn_s_memrealtime();
    while (__hip_atomic_load(bar, __ATOMIC_RELAXED, __HIP_MEMORY_SCOPE_AGENT) < target){
      __builtin_amdgcn_s_sleep(2);
      if (__builtin_amdgcn_s_memrealtime() - t0 > SPIN_LIMIT) break;
    }
  }
  __syncthreads();
}

// copy a 128x128 fp32 matrix global->LDS, NT threads
template<int NT>
__device__ __forceinline__ void load_W(float* Wl, const float* g, int tid){
  #pragma unroll
  for (int c = 0; c < (HID*HID/4)/NT; ++c){
    int e = (c*NT + tid)*4;
    *reinterpret_cast<float4*>(Wl + e) = *reinterpret_cast<const float4*>(g + e);
  }
}

// one row, 4 cols: o[j] = sum_k yt[rs][k]*Wl[k][fg*4+j]
__device__ __forceinline__ void gemm128_1(const float* Wl, const float* yt, int fg, int rs,
                                          float o[4]){
  float a0[4]={0.f,0.f,0.f,0.f};
  #pragma unroll 4
  for (int k=0;k<HID;k+=4){
    float4 ya = *reinterpret_cast<const float4*>(yt + rs*HID + k);
    #pragma unroll
    for (int kk=0;kk<4;++kk){
      const float* wr = Wl + (k+kk)*HID + fg*4;
      float av = (&ya.x)[kk];
      #pragma unroll
      for (int i=0;i<4;++i) a0[i] = fmaf(wr[i], av, a0[i]);
    }
  }
  #pragma unroll
  for (int i=0;i<4;++i) o[i]=a0[i];
}

// two rows (rs, rs+RSTEP), 4 cols — used by out_kernel
template<int RSTEP>
__device__ __forceinline__ void gemm128(const float* Wl, const float* yt, int fg, int rs,
                                        float o0[4], float o1[4]){
  float a0[4]={0.f,0.f,0.f,0.f}, a1[4]={0.f,0.f,0.f,0.f};
  #pragma unroll 4
  for (int k=0;k<HID;k+=4){
    float4 ya = *reinterpret_cast<const float4*>(yt + rs*HID + k);
    float4 yb = *reinterpret_cast<const float4*>(yt + (rs+RSTEP)*HID + k);
    #pragma unroll
    for (int kk=0;kk<4;++kk){
      const float* wr = Wl + (k+kk)*HID + fg*4;
      float av = (&ya.x)[kk];
      float bv = (&yb.x)[kk];
      #pragma unroll
      for (int i=0;i<4;++i){
        float w = wr[i];
        a0[i] = fmaf(w, av, a0[i]);
        a1[i] = fmaf(w, bv, a1[i]);
      }
    }
  }
  #pragma unroll
  for (int i=0;i<4;++i){ o0[i]=a0[i]; o1[i]=a1[i]; }
}

// h = yt[rs] @ Wl (1 row x 4 cols/thread); h packed bf16 via one 8B agent
// store; own-row er (fp32) to LDS. el is NOT materialized — consumers
// recompute it from the bf16 h they load anyway.
__device__ __forceinline__ void gemm_epi(const float* Wl, const float* yt,
    int fg, int rs, int rowF, bool actF,
    u16* __restrict__ h_wr, float* er_l, const float ar4[4])
{
  float o[4];
  gemm128_1(Wl, yt, fg, rs, o);
  u64 pk = (u64)f2bf(o[0]) | ((u64)f2bf(o[1])<<16)
         | ((u64)f2bf(o[2])<<32) | ((u64)f2bf(o[3])<<48);
  if (actF) st_agent_u64(h_wr + (size_t)rowF*HID + fg*4, pk);
  const int hd2 = fg >> 2;
  float er=0.f;
  #pragma unroll
  for (int i=0;i<4;++i) er = fmaf(o[i], ar4[i], er);
  er += __shfl_xor(er,1); er += __shfl_xor(er,2);
  if ((fg & 3) == 0 && actF) er_l[rs*NHEAD + hd2] = er;
}

// Build CSR (edges sorted by dst); zero the 8 per-batch barrier counters.
__global__ void csr_kernel(const int* __restrict__ src, const int* __restrict__ dst,
                           int* __restrict__ row_start, int* __restrict__ edge_src,
                           int* __restrict__ bar){
  __shared__ int cnt[1024];
  __shared__ int scanb[1024];
  __shared__ int cur[1024];
  int tid = threadIdx.x;
  if (tid < NBATCH*BARSTRIDE) bar[tid] = 0;
  cnt[tid] = 0;
  __syncthreads();
  for (int e = tid; e < NEDGE; e += 1024) atomicAdd(&cnt[dst[e]], 1);
  __syncthreads();
  int v = cnt[tid];
  scanb[tid] = v;
  __syncthreads();
  for (int off=1; off<1024; off<<=1){
    int t = (tid >= off) ? scanb[tid-off] : 0;
    __syncthreads();
    scanb[tid] += t;
    __syncthreads();
  }
  int incl = scanb[tid];
  if (tid < NNODE){ cur[tid] = incl - v; row_start[tid+1] = incl; }
  if (tid == 0) row_start[0] = 0;
  __syncthreads();
  for (int e = tid; e < NEDGE; e += 1024){
    int d = dst[e];
    int pos = atomicAdd(&cur[d], 1);
    edge_src[pos] = src[e];
  }
}

struct PArgs {
  u16* hb0; u16* hb1; float* y_out;
  const int* row_start; const int* edge_src;
  const float* w_gat; const float* a_l; const float* a_r;
  const float* inputs; const float* w_in; const float* b_in;
  const float* w_W; const float* b_W; const float* w_U; const float* b_U;
  int* bar;
};

__global__ void __launch_bounds__(PTHREADS, 4) persist(PArgs p)
{
  __shared__ float Wl[HID*HID];      // 64 KB — w_gat resident except around GRU
  __shared__ float yt[RPB*HID];      // 16 KB
  __shared__ int   esrc_l[ECAP];     // 3 KB
  __shared__ int   eoff[RPB+1];
  __shared__ int   degs_s[RPB];
  __shared__ float er_l[RPB*NHEAD];  // ~86 KB total -> 1 block/CU, 16 waves

  const int tid  = threadIdx.x;
  // batch grouping doubles as XCD-locality heuristic (blockIdx%8 -> XCD)
  const int bat   = blockIdx.x & 7;            // batch index
  const int slot  = blockIdx.x >> 3;           // 0..31
  const int row0  = bat * NNODE + slot * RPB;
  const int nrows = (slot == 31) ? (NNODE - 31*RPB) : RPB;   // 8 or 32
  int* const bar_b = p.bar + bat * BARSTRIDE;
  // layout A (gather): 16 threads x 2 edge-segments per row, 32 rows
  const int tA = tid & 15, seg = (tid >> 4) & 1, rA = tid >> 5;
  const bool actA = rA < nrows;
  const int nA     = slot*RPB + rA;            // node within batch
  const int nAs    = actA ? nA : 0;
  const int sbase  = bat * NNODE;
  const int hd   = tA >> 1;
  const int off8 = tA * 8;
  // layout F (GEMM): 32 col-groups (4 cols) x 32 rows, all 1024 threads
  const int fg = tid & 31, rs = tid >> 5;
  const bool actF = rs < nrows;
  const int rowF = row0 + rs;
  const int hd2 = fg >> 2, db = (fg & 3) * 4;

  // ---- one-time: per-block edge cache ----
  int s0r = 0, degr = 0;
  if (actA){ s0r = p.row_start[nA]; degr = p.row_start[nA+1] - s0r; }
  if ((tid & 31) == 0) degs_s[rA] = degr;
  __syncthreads();
  if (tid == 0){
    int o = 0;
    #pragma unroll
    for (int r = 0; r < RPB; ++r){ eoff[r] = o; o += degs_s[r]; }
    eoff[RPB] = o;
  }
  __syncthreads();
  const int* eptr;
  if (eoff[RPB] <= ECAP){
    const int eb = eoff[rA];
    for (int e = tA + 16*seg; e < degr; e += 32) esrc_l[eb + e] = p.edge_src[s0r + e];
    eptr = esrc_l + eb;
  } else {
    eptr = p.edge_src + s0r;   // statistically never; correctness fallback
  }

  // ---- one-time: per-thread constants ----
  // gather lane: a_l slice for its 8 dims (head hd, half tA&1)
  float alA[8];
  #pragma unroll
  for (int i=0;i<8;++i) alA[i] = p.a_l[hd*DHEAD + (tA&1)*8 + i];
  // epilogue lane: a_r slice for its 4 cols
  float ar4[4];
  #pragma unroll
  for (int i=0;i<4;++i) ar4[i] = p.a_r[hd2*DHEAD + db + i];

  load_W<PTHREADS>(Wl, p.w_gat, tid);

  // ---- init: y0 = inputs[:,0]@w_in + b_in ----
  float yb8[8], ya8[8];
  {
    const float x0 = p.inputs[((bat*SEQL + 0)*NNODE + nAs)*2 + 0];
    const float x1 = p.inputs[((bat*SEQL + 0)*NNODE + nAs)*2 + 1];
    #pragma unroll
    for (int i=0;i<8;++i){
      int f = off8 + i;
      yb8[i] = x0*p.w_in[f] + x1*p.w_in[HID+f] + p.b_in[f];
    }
    if (seg == 0){
      *reinterpret_cast<float4*>(yt + rA*HID + off8)     = make_float4(yb8[0],yb8[1],yb8[2],yb8[3]);
      *reinterpret_cast<float4*>(yt + rA*HID + off8 + 4) = make_float4(yb8[4],yb8[5],yb8[6],yb8[7]);
    }
  }
  __syncthreads();     // yt, Wl, esrc_l staged
  gemm_epi(Wl, yt, fg, rs, rowF, actF, p.hb0, er_l, ar4);

  int step = 1;
  grid_bar(bar_b, NBLK_B * step); ++step;

  // per-segment edge range (contiguous halves)
  const int half0 = (degr + 1) >> 1;
  const int e_lo = seg ? half0 : 0;
  const int e_hi = seg ? degr  : half0;

  int rd = 0;
  for (int idx = 0; idx < SEQL; ++idx){
    for (int st = 0; st < 4; ++st){
      for (int j = 1; j <= 4; ++j){
        const u16* __restrict__ h_rd = rd ? p.hb1 : p.hb0;
        u16* __restrict__ h_wr       = rd ? p.hb0 : p.hb1;

        // ---- gather: softmax aggregation; el recomputed from bf16 h ----
        float acc[8] = {0.f,0.f,0.f,0.f,0.f,0.f,0.f,0.f};
        float sum = 0.f;
        {
          const float erh = er_l[rA*NHEAD + hd];
          int e = e_lo;
          for (; e + 4 <= e_hi; e += 4){
            u64 L[4], H[4];
            #pragma unroll
            for (int q=0;q<4;++q){
              const int s = sbase + eptr[e+q];
              const u16* hp = h_rd + (size_t)s*HID + off8;
              L[q] = ld_agent_u64(hp);
              H[q] = ld_agent_u64(hp + 4);
            }
            #pragma unroll
            for (int q=0;q<4;++q){
              float hv[8];
              hv[0]=bf2f((u16)L[q]);       hv[1]=bf2f((u16)(L[q]>>16));
              hv[2]=bf2f((u16)(L[q]>>32)); hv[3]=bf2f((u16)(L[q]>>48));
              hv[4]=bf2f((u16)H[q]);       hv[5]=bf2f((u16)(H[q]>>16));
              hv[6]=bf2f((u16)(H[q]>>32)); hv[7]=bf2f((u16)(H[q]>>48));
              float ep = 0.f;
              #pragma unroll
              for (int i=0;i<8;++i) ep = fmaf(alA[i], hv[i], ep);
              ep += __shfl_xor(ep, 1);           // full el over 16 dims
              const float x = ep + erh;
              const float w = __expf(fminf(fmaxf(x, 0.2f*x), 30.f));
              sum += w;
              #pragma unroll
              for (int i=0;i<8;++i) acc[i] = fmaf(w, hv[i], acc[i]);
            }
          }
          for (; e < e_hi; ++e){
            const int s = sbase + eptr[e];
            const u16* hp = h_rd + (size_t)s*HID + off8;
            const u64 L = ld_agent_u64(hp);
            const u64 H = ld_agent_u64(hp + 4);
            float hv[8];
            hv[0]=bf2f((u16)L);       hv[1]=bf2f((u16)(L>>16));
            hv[2]=bf2f((u16)(L>>32)); hv[3]=bf2f((u16)(L>>48));
            hv[4]=bf2f((u16)H);       hv[5]=bf2f((u16)(H>>16));
            hv[6]=bf2f((u16)(H>>32)); hv[7]=bf2f((u16)(H>>48));
            float ep = 0.f;
            #pragma unroll
            for (int i=0;i<8;++i) ep = fmaf(alA[i], hv[i], ep);
            ep += __shfl_xor(ep, 1);
            const float x = ep + erh;
            const float w = __expf(fminf(fmaxf(x, 0.2f*x), 30.f));
            sum += w;
            #pragma unroll
            for (int i=0;i<8;++i) acc[i] = fmaf(w, hv[i], acc[i]);
          }
        }
        // combine the two segments (lane ^ 16 = same row, other segment)
        sum += __shfl_xor(sum, 16);
        #pragma unroll
        for (int i=0;i<8;++i) acc[i] += __shfl_xor(acc[i], 16);
        const float inv = 1.f / (sum + 1e-16f);
        #pragma unroll
        for (int i=0;i<8;++i) acc[i] *= inv;

        // ---- RK4 register update (duplicated in both segs, identical) ----
        const bool is5 = (st == 3) && (j == 4);
        float nxt[8];
        if (j == 1){
          #pragma unroll
          for (int i=0;i<8;++i){ ya8[i] = fmaf(DT/6.f, acc[i], yb8[i]);
                                 nxt[i] = fmaf(0.5f*DT, acc[i], yb8[i]); }
        } else if (j == 2){
          #pragma unroll
          for (int i=0;i<8;++i){ ya8[i] = fmaf(DT/3.f, acc[i], ya8[i]);
                                 nxt[i] = fmaf(0.5f*DT, acc[i], yb8[i]); }
        } else if (j == 3){
          #pragma unroll
          for (int i=0;i<8;++i){ ya8[i] = fmaf(DT/3.f, acc[i], ya8[i]);
                                 nxt[i] = fmaf(DT, acc[i], yb8[i]); }
        } else {
          #pragma unroll
          for (int i=0;i<8;++i) nxt[i] = fmaf(DT/6.f, acc[i], ya8[i]);
          if (!is5){
            #pragma unroll
            for (int i=0;i<8;++i) yb8[i] = nxt[i];
          }
        }

        if (seg == 0){
          *reinterpret_cast<float4*>(yt + rA*HID + off8)     = make_float4(nxt[0],nxt[1],nxt[2],nxt[3]);
          *reinterpret_cast<float4*>(yt + rA*HID + off8 + 4) = make_float4(nxt[4],nxt[5],nxt[6],nxt[7]);
        }

        if (!is5){
          __syncthreads();
          gemm_epi(Wl, yt, fg, rs, rowF, actF, h_wr, er_l, ar4);
          grid_bar(bar_b, NBLK_B * step); ++step;
          rd ^= 1;
          continue;
        }

        // ---- end of interval: optional GRU, LN, state handoff ----
        const bool last = (idx == SEQL-1);
        float z[4];
        if (idx > 0){
          load_W<PTHREADS>(Wl, p.w_W, tid);
          __syncthreads();                       // yt(y_new) + w_W ready
          gemm128_1(Wl, yt, fg, rs, z);          // z = y_new @ w_W
          __syncthreads();                       // gemm reads done
          {
            const float x0 = p.inputs[((bat*SEQL + idx)*NNODE + nAs)*2 + 0];
            const float x1 = p.inputs[((bat*SEQL + idx)*NNODE + nAs)*2 + 1];
            if (seg == 0){
              float hv[8];
              #pragma unroll
              for (int i=0;i<8;++i){
                int f = off8 + i;
                hv[i] = x0*p.w_in[f] + x1*p.w_in[HID+f] + p.b_in[f];
              }
              *reinterpret_cast<float4*>(yt + rA*HID + off8)     = make_float4(hv[0],hv[1],hv[2],hv[3]);
              *reinterpret_cast<float4*>(yt + rA*HID + off8 + 4) = make_float4(hv[4],hv[5],hv[6],hv[7]);
            }
          }
          load_W<PTHREADS>(Wl, p.w_U, tid);
          __syncthreads();
          float u[4];
          gemm128_1(Wl, yt, fg, rs, u);          // u = h_in @ w_U
          #pragma unroll
          for (int i=0;i<4;++i)
            z[i] = tanhf(z[i] + u[i] + p.b_W[fg*4+i] + p.b_U[fg*4+i]);
        } else {
          __syncthreads();                       // yt(y_new) visible in F layout
          #pragma unroll
          for (int i=0;i<4;++i) z[i] = yt[rs*HID + fg*4 + i];
        }
        // LayerNorm over 128 features (32 fg lanes)
        {
          float sv=0.f, qv=0.f;
          #pragma unroll
          for (int i=0;i<4;++i){ sv+=z[i]; qv+=z[i]*z[i]; }
          #pragma unroll
          for (int off=1; off<32; off<<=1){
            sv += __shfl_xor(sv, off); qv += __shfl_xor(qv, off);
          }
          float mu = sv*(1.f/HID);
          float r  = rsqrtf(qv*(1.f/HID) - mu*mu + 1e-5f);
          #pragma unroll
          for (int i=0;i<4;++i) z[i] = (z[i]-mu)*r;
        }
        __syncthreads();                         // all yt readers done
        *reinterpret_cast<float4*>(yt + rs*HID + fg*4) = make_float4(z[0],z[1],z[2],z[3]);
        if (last && actF)
          *reinterpret_cast<float4*>(p.y_out + (size_t)rowF*HID + fg*4) = make_float4(z[0],z[1],z[2],z[3]);
        if (!last){
          if (idx > 0) load_W<PTHREADS>(Wl, p.w_gat, tid);  // restore resident w_gat
          __syncthreads();
          #pragma unroll
          for (int i=0;i<8;++i) yb8[i] = yt[rA*HID + off8 + i];  // new y state
          gemm_epi(Wl, yt, fg, rs, rowF, actF, h_wr, er_l, ar4);
          grid_bar(bar_b, NBLK_B * step); ++step;
          rd ^= 1;
        }
        // last: no more barriers; blocks exit; kernel boundary flushes caches
      }
    }
  }
}

// out = tanh(ret @ w_o1 + b_o1) @ w_o2 + b_o2, fp32 output
__global__ void __launch_bounds__(256, 2) out_kernel(
    const float* __restrict__ y_base,
    const float* __restrict__ w_o1, const float* __restrict__ b_o1,
    const float* __restrict__ w_o2, const float* __restrict__ b_o2,
    float* __restrict__ out)
{
  __shared__ float Wl[HID*HID];
  __shared__ float yt[ORPB*HID];
  const int tid = threadIdx.x;
  const int row0 = blockIdx.x * ORPB;
  const int rA = tid >> 4, tA = tid & 15;
  const int rowA = row0 + rA;
  {
    float4 v0 = *reinterpret_cast<const float4*>(y_base + rowA*HID + tA*8);
    float4 v1 = *reinterpret_cast<const float4*>(y_base + rowA*HID + tA*8 + 4);
    *reinterpret_cast<float4*>(yt + rA*HID + tA*8)     = v0;
    *reinterpret_cast<float4*>(yt + rA*HID + tA*8 + 4) = v1;
  }
  load_W<256>(Wl, w_o1, tid);
  __syncthreads();
  const int fg = tid & 31, rs = tid >> 5;
  float t0[4], t1[4];
  gemm128<8>(Wl, yt, fg, rs, t0, t1);
  #pragma unroll
  for (int i=0;i<4;++i){
    float bb = b_o1[fg*4+i];
    t0[i] = tanhf(t0[i] + bb);
    t1[i] = tanhf(t1[i] + bb);
  }
  __syncthreads();
  *reinterpret_cast<float4*>(yt + rs*HID + fg*4)     = make_float4(t0[0],t0[1],t0[2],t0[3]);
  *reinterpret_cast<float4*>(yt + (rs+8)*HID + fg*4) = make_float4(t1[0],t1[1],t1[2],t1[3]);
  load_W<256>(Wl, w_o2, tid);
  __syncthreads();
  float o0[4], o1[4];
  gemm128<8>(Wl, yt, fg, rs, o0, o1);
  const int rowF0 = row0 + rs, rowF1 = row0 + rs + 8;
  *reinterpret_cast<float4*>(out + rowF0*HID + fg*4) =
      make_float4(o0[0]+b_o2[fg*4+0], o0[1]+b_o2[fg*4+1], o0[2]+b_o2[fg*4+2], o0[3]+b_o2[fg*4+3]);
  *reinterpret_cast<float4*>(out + rowF1*HID + fg*4) =
      make_float4(o1[0]+b_o2[fg*4+0], o1[1]+b_o2[fg*4+1], o1[2]+b_o2[fg*4+2], o1[3]+b_o2[fg*4+3]);
}

extern "C" void kernel_launch(void* const* d_in, const int* in_sizes, int n_in,
                              void* d_out, int out_size, void* d_ws, size_t ws_size,
                              hipStream_t stream)
{
  const float* inputs = (const float*)d_in[0];
  const int* src      = (const int*)d_in[1];
  const int* dst      = (const int*)d_in[2];
  const float* w_in   = (const float*)d_in[3];
  const float* b_in   = (const float*)d_in[4];
  const float* w_gat  = (const float*)d_in[5];
  const float* a_l    = (const float*)d_in[6];
  const float* a_r    = (const float*)d_in[7];
  const float* w_W    = (const float*)d_in[8];
  const float* b_W    = (const float*)d_in[9];
  const float* w_U    = (const float*)d_in[10];
  const float* b_U    = (const float*)d_in[11];
  const float* w_o1   = (const float*)d_in[12];
  const float* b_o1   = (const float*)d_in[13];
  const float* w_o2   = (const float*)d_in[14];
  const float* b_o2   = (const float*)d_in[15];

  const size_t RH = (size_t)NROWS * HID;    // 1,024,000
  float* y_out = reinterpret_cast<float*>(d_ws);            // RH floats
  u16*   hbuf  = reinterpret_cast<u16*>(y_out + RH);        // 2*RH bf16
  u16*   hb0   = hbuf;
  u16*   hb1   = hbuf + RH;
  int*   I     = reinterpret_cast<int*>(hbuf + 2*RH);
  int* row_start = I;
  int* edge_src  = I + 1024;
  int* bar       = I + 1024 + NEDGE;

  size_t need = RH*sizeof(float) + 2*RH*sizeof(u16)
              + (size_t)(1024 + NEDGE + NBATCH*BARSTRIDE)*sizeof(int);
  if (ws_size < need) return;

  csr_kernel<<<1, 1024, 0, stream>>>(src, dst, row_start, edge_src, bar);

  PArgs pa;
  pa.hb0 = hb0; pa.hb1 = hb1; pa.y_out = y_out;
  pa.row_start = row_start; pa.edge_src = edge_src;
  pa.w_gat = w_gat; pa.a_l = a_l; pa.a_r = a_r;
  pa.inputs = inputs; pa.w_in = w_in; pa.b_in = b_in;
  pa.w_W = w_W; pa.b_W = b_W; pa.w_U = w_U; pa.b_U = b_U;
  pa.bar = bar;

  persist<<<NBLK_P, PTHREADS, 0, stream>>>(pa);

  out_kernel<<<NBLK_O, 256, 0, stream>>>(y_out, w_o1, b_o1, w_o2, b_o2, (float*)d_out);
}

// Round 10
// 2759.592 us; speedup vs baseline: 2.6363x; 1.0426x over previous
//
#include <hip/hip_runtime.h>

#define NNODE 1000
#define NBATCH 8
#define SEQL 12
#define NHEAD 8
#define DHEAD 16
#define HID 128
#define NEDGE 16000
#define NROWS (NBATCH*NNODE)   // 8000
#define RPB 32                 // rows per persistent block
#define NBLK_P 256             // 8 batch-groups x 32 slots; 1 block/CU
#define NBLK_B 32              // blocks per batch = barrier width
#define BARSTRIDE 64           // ints between per-batch counters (256 B)
#define PTHREADS 1024
#define ORPB 16
#define NBLK_O (NROWS/ORPB)    // 500
#define DT 0.25f
#define ECAP 768               // LDS edge cache (block mean 512)
#define SPIN_LIMIT 100000ULL   // 1 ms escape hatch (finite wrong-run, not hang)
#define WSTRIDE 136            // padded K-stride (u16) -> 2-way-free LDS banks
#define WLO (128*WSTRIDE)      // u16 offset of the lo-residual matrix

typedef unsigned short u16;
typedef unsigned int   u32;
typedef unsigned long long u64;
typedef __attribute__((ext_vector_type(8))) short bf16x8;
typedef __attribute__((ext_vector_type(4))) float f32x4;

__device__ __forceinline__ u16 f2bf(float f){
  u32 x = __float_as_uint(f);
  return (u16)((x + 0x7fffu + ((x>>16)&1u)) >> 16);
}
__device__ __forceinline__ float bf2f(u16 u){ return __uint_as_float(((u32)u)<<16); }

// ---- agent-scope (MALL point-of-coherence) h exchange ----
__device__ __forceinline__ u64 ld_agent_u64(const u16* p){
  return __hip_atomic_load(reinterpret_cast<const u64*>(p),
                           __ATOMIC_RELAXED, __HIP_MEMORY_SCOPE_AGENT);
}
__device__ __forceinline__ void st_agent_u64(u16* p, u64 v){
  __hip_atomic_store(reinterpret_cast<u64*>(p), v,
                     __ATOMIC_RELAXED, __HIP_MEMORY_SCOPE_AGENT);
}

// ---- per-batch barrier: release fetch_add orders prior sc1 stores; no fences ----
__device__ __forceinline__ void grid_bar(int* bar, int target){
  __syncthreads();
  if (threadIdx.x == 0){
    __hip_atomic_fetch_add(bar, 1, __ATOMIC_RELEASE, __HIP_MEMORY_SCOPE_AGENT);
    unsigned long long t0 = __builtin_amdgcn_s_memrealtime();
    while (__hip_atomic_load(bar, __ATOMIC_RELAXED, __HIP_MEMORY_SCOPE_AGENT) < target){
      __builtin_amdgcn_s_sleep(2);
      if (__builtin_amdgcn_s_memrealtime() - t0 > SPIN_LIMIT) break;
    }
  }
  __syncthreads();
}

// copy a 128x128 fp32 matrix global->LDS, NT threads (GRU + out_kernel path)
template<int NT>
__device__ __forceinline__ void load_W(float* Wl, const float* g, int tid){
  #pragma unroll
  for (int c = 0; c < (HID*HID/4)/NT; ++c){
    int e = (c*NT + tid)*4;
    *reinterpret_cast<float4*>(Wl + e) = *reinterpret_cast<const float4*>(g + e);
  }
}

// split-precision transposed load: W[k][n] fp32 -> WbT[n][k] hi/lo bf16
__device__ __forceinline__ void load_WT_split(u16* WbT, const float* g, int tid){
  #pragma unroll
  for (int c = 0; c < 16; ++c){
    int flat = c*PTHREADS + tid;        // = k*128 + n
    int k = flat >> 7, n = flat & 127;
    float v = g[flat];
    u16 hi = f2bf(v);
    u16 lo = f2bf(v - bf2f(hi));
    WbT[n*WSTRIDE + k]       = hi;
    WbT[WLO + n*WSTRIDE + k] = lo;
  }
}

// one row, 4 cols: o[j] = sum_k yt[rs][k]*Wl[k][fg*4+j]  (fp32, GRU path)
__device__ __forceinline__ void gemm128_1(const float* Wl, const float* yt, int fg, int rs,
                                          float o[4]){
  float a0[4]={0.f,0.f,0.f,0.f};
  #pragma unroll 4
  for (int k=0;k<HID;k+=4){
    float4 ya = *reinterpret_cast<const float4*>(yt + rs*HID + k);
    #pragma unroll
    for (int kk=0;kk<4;++kk){
      const float* wr = Wl + (k+kk)*HID + fg*4;
      float av = (&ya.x)[kk];
      #pragma unroll
      for (int i=0;i<4;++i) a0[i] = fmaf(wr[i], av, a0[i]);
    }
  }
  #pragma unroll
  for (int i=0;i<4;++i) o[i]=a0[i];
}

// two rows (rs, rs+RSTEP), 4 cols — used by out_kernel
template<int RSTEP>
__device__ __forceinline__ void gemm128(const float* Wl, const float* yt, int fg, int rs,
                                        float o0[4], float o1[4]){
  float a0[4]={0.f,0.f,0.f,0.f}, a1[4]={0.f,0.f,0.f,0.f};
  #pragma unroll 4
  for (int k=0;k<HID;k+=4){
    float4 ya = *reinterpret_cast<const float4*>(yt + rs*HID + k);
    float4 yb = *reinterpret_cast<const float4*>(yt + (rs+RSTEP)*HID + k);
    #pragma unroll
    for (int kk=0;kk<4;++kk){
      const float* wr = Wl + (k+kk)*HID + fg*4;
      float av = (&ya.x)[kk];
      float bv = (&yb.x)[kk];
      #pragma unroll
      for (int i=0;i<4;++i){
        float w = wr[i];
        a0[i] = fmaf(w, av, a0[i]);
        a1[i] = fmaf(w, bv, a1[i]);
      }
    }
  }
  #pragma unroll
  for (int i=0;i<4;++i){ o0[i]=a0[i]; o1[i]=a1[i]; }
}

// pack 8 fp32 -> 8 bf16 into yt_bf[rA][off8..off8+7]
__device__ __forceinline__ void pack_y(u16* yt_bf, int rA, int off8, const float y[8]){
  uint4 w;
  w.x = (u32)f2bf(y[0]) | ((u32)f2bf(y[1])<<16);
  w.y = (u32)f2bf(y[2]) | ((u32)f2bf(y[3])<<16);
  w.z = (u32)f2bf(y[4]) | ((u32)f2bf(y[5])<<16);
  w.w = (u32)f2bf(y[6]) | ((u32)f2bf(y[7])<<16);
  *reinterpret_cast<uint4*>(yt_bf + rA*WSTRIDE + off8) = w;
}

// MFMA h-stage: yt_bf holds y (bf16); WbT holds w_gat^T hi/lo.
// Computes h = y @ W (fp32 acc, W exact via hi+lo), writes h bf16 back into
// yt_bf, then wire-stores packed u64 + er epilogue. Caller synced before.
__device__ __forceinline__ void h_stage(u16* yt_bf, const u16* WbT,
    int mt, int nt, int quad, int lc,
    int fg, int rs, int rowF, bool actF,
    u16* __restrict__ h_wr, float* er_l, const float ar4[4])
{
  f32x4 c = {0.f, 0.f, 0.f, 0.f};
  const u16* arow = yt_bf + (mt*16 + lc)*WSTRIDE;
  const u16* brow = WbT  + (nt*16 + lc)*WSTRIDE;
  #pragma unroll
  for (int k0 = 0; k0 < 4; ++k0){
    const int off = k0*32 + quad*8;
    bf16x8 a  = *reinterpret_cast<const bf16x8*>(arow + off);
    bf16x8 bh = *reinterpret_cast<const bf16x8*>(brow + off);
    bf16x8 bl = *reinterpret_cast<const bf16x8*>(brow + WLO + off);
    c = __builtin_amdgcn_mfma_f32_16x16x32_bf16(a, bh, c, 0, 0, 0);
    c = __builtin_amdgcn_mfma_f32_16x16x32_bf16(a, bl, c, 0, 0, 0);
  }
  __syncthreads();              // all A-reads of yt_bf complete
  {
    const int col = nt*16 + lc;
    #pragma unroll
    for (int r = 0; r < 4; ++r)
      yt_bf[(mt*16 + quad*4 + r)*WSTRIDE + col] = f2bf(c[r]);
  }
  __syncthreads();              // h bf16 visible block-wide
  // pack-store + er (F layout: fg = 4-col group, rs = row)
  const u64 pk = *reinterpret_cast<const u64*>(yt_bf + rs*WSTRIDE + fg*4);
  if (actF) st_agent_u64(h_wr + (size_t)rowF*HID + fg*4, pk);
  float er = 0.f;
  er = fmaf(bf2f((u16)pk),       ar4[0], er);
  er = fmaf(bf2f((u16)(pk>>16)), ar4[1], er);
  er = fmaf(bf2f((u16)(pk>>32)), ar4[2], er);
  er = fmaf(bf2f((u16)(pk>>48)), ar4[3], er);
  er += __shfl_xor(er,1); er += __shfl_xor(er,2);
  if ((fg & 3) == 0 && actF) er_l[rs*NHEAD + (fg>>2)] = er;
}

// Build CSR (edges sorted by dst); zero the 8 per-batch barrier counters.
__global__ void csr_kernel(const int* __restrict__ src, const int* __restrict__ dst,
                           int* __restrict__ row_start, int* __restrict__ edge_src,
                           int* __restrict__ bar){
  __shared__ int cnt[1024];
  __shared__ int scanb[1024];
  __shared__ int cur[1024];
  int tid = threadIdx.x;
  if (tid < NBATCH*BARSTRIDE) bar[tid] = 0;
  cnt[tid] = 0;
  __syncthreads();
  for (int e = tid; e < NEDGE; e += 1024) atomicAdd(&cnt[dst[e]], 1);
  __syncthreads();
  int v = cnt[tid];
  scanb[tid] = v;
  __syncthreads();
  for (int off=1; off<1024; off<<=1){
    int t = (tid >= off) ? scanb[tid-off] : 0;
    __syncthreads();
    scanb[tid] += t;
    __syncthreads();
  }
  int incl = scanb[tid];
  if (tid < NNODE){ cur[tid] = incl - v; row_start[tid+1] = incl; }
  if (tid == 0) row_start[0] = 0;
  __syncthreads();
  for (int e = tid; e < NEDGE; e += 1024){
    int d = dst[e];
    int pos = atomicAdd(&cur[d], 1);
    edge_src[pos] = src[e];
  }
}

struct PArgs {
  u16* hb0; u16* hb1; float* y_out;
  const int* row_start; const int* edge_src;
  const float* w_gat; const float* a_l; const float* a_r;
  const float* inputs; const float* w_in; const float* b_in;
  const float* w_W; const float* b_W; const float* w_U; const float* b_U;
  int* bar;
};

__global__ void __launch_bounds__(PTHREADS, 4) persist(PArgs p)
{
  __shared__ __align__(16) u16 WbT[2*128*WSTRIDE];  // 68 KB: w_gat^T hi/lo (bf16)
  __shared__ __align__(16) u16 yt_bf[RPB*WSTRIDE];  // 8.5 KB: y then h (bf16)
  __shared__ float zt[RPB*HID];                     // 16 KB: fp32 GRU/LN staging
  __shared__ int   esrc_l[ECAP];
  __shared__ int   eoff[RPB+1];
  __shared__ int   degs_s[RPB];
  __shared__ float er_l[RPB*NHEAD];                 // total ~98 KB -> 1 block/CU
  float* const Wlf = reinterpret_cast<float*>(WbT); // 64 KB fp32 overlay (GRU)

  const int tid  = threadIdx.x;
  const int bat   = blockIdx.x & 7;            // batch index (XCD heuristic)
  const int slot  = blockIdx.x >> 3;           // 0..31
  const int row0  = bat * NNODE + slot * RPB;
  const int nrows = (slot == 31) ? (NNODE - 31*RPB) : RPB;   // 8 or 32
  int* const bar_b = p.bar + bat * BARSTRIDE;
  // layout A (gather): 16 threads x 2 edge-segments per row, 32 rows
  const int tA = tid & 15, seg = (tid >> 4) & 1, rA = tid >> 5;
  const bool actA = rA < nrows;
  const int nA     = slot*RPB + rA;
  const int nAs    = actA ? nA : 0;
  const int sbase  = bat * NNODE;
  const int hd   = tA >> 1;
  const int off8 = tA * 8;
  // layout F (epilogue/LN): 32 col-groups (4 cols) x 32 rows
  const int fg = tid & 31, rs = tid >> 5;
  const bool actF = rs < nrows;
  const int rowF = row0 + rs;
  const int hd2 = fg >> 2, db = (fg & 3) * 4;
  // MFMA ids: 16 waves = 2 M-tiles x 8 N-tiles
  const int wv = tid >> 6, lane = tid & 63, quad = lane >> 4, lc = lane & 15;
  const int mt = wv & 1, nt = wv >> 1;

  // ---- one-time: per-block edge cache ----
  int s0r = 0, degr = 0;
  if (actA){ s0r = p.row_start[nA]; degr = p.row_start[nA+1] - s0r; }
  if ((tid & 31) == 0) degs_s[rA] = degr;
  __syncthreads();
  if (tid == 0){
    int o = 0;
    #pragma unroll
    for (int r = 0; r < RPB; ++r){ eoff[r] = o; o += degs_s[r]; }
    eoff[RPB] = o;
  }
  __syncthreads();
  const int* eptr;
  if (eoff[RPB] <= ECAP){
    const int eb = eoff[rA];
    for (int e = tA + 16*seg; e < degr; e += 32) esrc_l[eb + e] = p.edge_src[s0r + e];
    eptr = esrc_l + eb;
  } else {
    eptr = p.edge_src + s0r;   // statistically never; correctness fallback
  }

  // ---- one-time: per-thread constants ----
  float alA[8];
  #pragma unroll
  for (int i=0;i<8;++i) alA[i] = p.a_l[hd*DHEAD + (tA&1)*8 + i];
  float ar4[4];
  #pragma unroll
  for (int i=0;i<4;++i) ar4[i] = p.a_r[hd2*DHEAD + db + i];

  load_WT_split(WbT, p.w_gat, tid);

  // ---- init: y0 = inputs[:,0]@w_in + b_in ----
  float yb8[8], ya8[8];
  {
    const float x0 = p.inputs[((bat*SEQL + 0)*NNODE + nAs)*2 + 0];
    const float x1 = p.inputs[((bat*SEQL + 0)*NNODE + nAs)*2 + 1];
    #pragma unroll
    for (int i=0;i<8;++i){
      int f = off8 + i;
      yb8[i] = x0*p.w_in[f] + x1*p.w_in[HID+f] + p.b_in[f];
    }
    if (seg == 0) pack_y(yt_bf, rA, off8, yb8);
  }
  __syncthreads();     // yt_bf, WbT, esrc_l staged
  h_stage(yt_bf, WbT, mt, nt, quad, lc, fg, rs, rowF, actF, p.hb0, er_l, ar4);

  int step = 1;
  grid_bar(bar_b, NBLK_B * step); ++step;

  // per-segment edge range (contiguous halves)
  const int half0 = (degr + 1) >> 1;
  const int e_lo = seg ? half0 : 0;
  const int e_hi = seg ? degr  : half0;

  int rd = 0;
  for (int idx = 0; idx < SEQL; ++idx){
    for (int st = 0; st < 4; ++st){
      for (int j = 1; j <= 4; ++j){
        const u16* __restrict__ h_rd = rd ? p.hb1 : p.hb0;
        u16* __restrict__ h_wr       = rd ? p.hb0 : p.hb1;

        // ---- gather: softmax aggregation; el recomputed from bf16 h ----
        float acc[8] = {0.f,0.f,0.f,0.f,0.f,0.f,0.f,0.f};
        float sum = 0.f;
        {
          const float erh = er_l[rA*NHEAD + hd];
          int e = e_lo;
          for (; e + 4 <= e_hi; e += 4){
            u64 L[4], H[4];
            #pragma unroll
            for (int q=0;q<4;++q){
              const int s = sbase + eptr[e+q];
              const u16* hp = h_rd + (size_t)s*HID + off8;
              L[q] = ld_agent_u64(hp);
              H[q] = ld_agent_u64(hp + 4);
            }
            #pragma unroll
            for (int q=0;q<4;++q){
              float hv[8];
              hv[0]=bf2f((u16)L[q]);       hv[1]=bf2f((u16)(L[q]>>16));
              hv[2]=bf2f((u16)(L[q]>>32)); hv[3]=bf2f((u16)(L[q]>>48));
              hv[4]=bf2f((u16)H[q]);       hv[5]=bf2f((u16)(H[q]>>16));
              hv[6]=bf2f((u16)(H[q]>>32)); hv[7]=bf2f((u16)(H[q]>>48));
              float ep = 0.f;
              #pragma unroll
              for (int i=0;i<8;++i) ep = fmaf(alA[i], hv[i], ep);
              ep += __shfl_xor(ep, 1);
              const float x = ep + erh;
              const float w = __expf(fminf(fmaxf(x, 0.2f*x), 30.f));
              sum += w;
              #pragma unroll
              for (int i=0;i<8;++i) acc[i] = fmaf(w, hv[i], acc[i]);
            }
          }
          for (; e < e_hi; ++e){
            const int s = sbase + eptr[e];
            const u16* hp = h_rd + (size_t)s*HID + off8;
            const u64 L = ld_agent_u64(hp);
            const u64 H = ld_agent_u64(hp + 4);
            float hv[8];
            hv[0]=bf2f((u16)L);       hv[1]=bf2f((u16)(L>>16));
            hv[2]=bf2f((u16)(L>>32)); hv[3]=bf2f((u16)(L>>48));
            hv[4]=bf2f((u16)H);       hv[5]=bf2f((u16)(H>>16));
            hv[6]=bf2f((u16)(H>>32)); hv[7]=bf2f((u16)(H>>48));
            float ep = 0.f;
            #pragma unroll
            for (int i=0;i<8;++i) ep = fmaf(alA[i], hv[i], ep);
            ep += __shfl_xor(ep, 1);
            const float x = ep + erh;
            const float w = __expf(fminf(fmaxf(x, 0.2f*x), 30.f));
            sum += w;
            #pragma unroll
            for (int i=0;i<8;++i) acc[i] = fmaf(w, hv[i], acc[i]);
          }
        }
        sum += __shfl_xor(sum, 16);
        #pragma unroll
        for (int i=0;i<8;++i) acc[i] += __shfl_xor(acc[i], 16);
        const float inv = 1.f / (sum + 1e-16f);
        #pragma unroll
        for (int i=0;i<8;++i) acc[i] *= inv;

        // ---- RK4 register update ----
        const bool is5 = (st == 3) && (j == 4);
        float nxt[8];
        if (j == 1){
          #pragma unroll
          for (int i=0;i<8;++i){ ya8[i] = fmaf(DT/6.f, acc[i], yb8[i]);
                                 nxt[i] = fmaf(0.5f*DT, acc[i], yb8[i]); }
        } else if (j == 2){
          #pragma unroll
          for (int i=0;i<8;++i){ ya8[i] = fmaf(DT/3.f, acc[i], ya8[i]);
                                 nxt[i] = fmaf(0.5f*DT, acc[i], yb8[i]); }
        } else if (j == 3){
          #pragma unroll
          for (int i=0;i<8;++i){ ya8[i] = fmaf(DT/3.f, acc[i], ya8[i]);
                                 nxt[i] = fmaf(DT, acc[i], yb8[i]); }
        } else {
          #pragma unroll
          for (int i=0;i<8;++i) nxt[i] = fmaf(DT/6.f, acc[i], ya8[i]);
          if (!is5){
            #pragma unroll
            for (int i=0;i<8;++i) yb8[i] = nxt[i];
          }
        }

        if (!is5){
          if (seg == 0) pack_y(yt_bf, rA, off8, nxt);
          __syncthreads();
          h_stage(yt_bf, WbT, mt, nt, quad, lc, fg, rs, rowF, actF, h_wr, er_l, ar4);
          grid_bar(bar_b, NBLK_B * step); ++step;
          rd ^= 1;
          continue;
        }

        // ---- end of interval: GRU (fp32 vector) / LN / state handoff ----
        const bool last = (idx == SEQL-1);
        if (seg == 0){
          *reinterpret_cast<float4*>(zt + rA*HID + off8)     = make_float4(nxt[0],nxt[1],nxt[2],nxt[3]);
          *reinterpret_cast<float4*>(zt + rA*HID + off8 + 4) = make_float4(nxt[4],nxt[5],nxt[6],nxt[7]);
        }
        float z4[4];
        if (idx > 0){
          load_W<PTHREADS>(Wlf, p.w_W, tid);     // overlays WbT (restored below)
          __syncthreads();                       // zt(y_new) + w_W ready
          gemm128_1(Wlf, zt, fg, rs, z4);        // z = y_new @ w_W
          __syncthreads();                       // gemm reads done
          {
            const float x0 = p.inputs[((bat*SEQL + idx)*NNODE + nAs)*2 + 0];
            const float x1 = p.inputs[((bat*SEQL + idx)*NNODE + nAs)*2 + 1];
            if (seg == 0){
              float hv[8];
              #pragma unroll
              for (int i=0;i<8;++i){
                int f = off8 + i;
                hv[i] = x0*p.w_in[f] + x1*p.w_in[HID+f] + p.b_in[f];
              }
              *reinterpret_cast<float4*>(zt + rA*HID + off8)     = make_float4(hv[0],hv[1],hv[2],hv[3]);
              *reinterpret_cast<float4*>(zt + rA*HID + off8 + 4) = make_float4(hv[4],hv[5],hv[6],hv[7]);
            }
          }
          load_W<PTHREADS>(Wlf, p.w_U, tid);
          __syncthreads();
          float u4[4];
          gemm128_1(Wlf, zt, fg, rs, u4);        // u = h_in @ w_U
          #pragma unroll
          for (int i=0;i<4;++i)
            z4[i] = tanhf(z4[i] + u4[i] + p.b_W[fg*4+i] + p.b_U[fg*4+i]);
        } else {
          __syncthreads();                       // zt(y_new) visible in F layout
          #pragma unroll
          for (int i=0;i<4;++i) z4[i] = zt[rs*HID + fg*4 + i];
        }
        // LayerNorm over 128 features (32 fg lanes)
        {
          float sv=0.f, qv=0.f;
          #pragma unroll
          for (int i=0;i<4;++i){ sv+=z4[i]; qv+=z4[i]*z4[i]; }
          #pragma unroll
          for (int off=1; off<32; off<<=1){
            sv += __shfl_xor(sv, off); qv += __shfl_xor(qv, off);
          }
          float mu = sv*(1.f/HID);
          float r  = rsqrtf(qv*(1.f/HID) - mu*mu + 1e-5f);
          #pragma unroll
          for (int i=0;i<4;++i) z4[i] = (z4[i]-mu)*r;
        }
        __syncthreads();                         // all zt readers done
        *reinterpret_cast<float4*>(zt + rs*HID + fg*4) = make_float4(z4[0],z4[1],z4[2],z4[3]);
        if (last){
          if (actF)
            *reinterpret_cast<float4*>(p.y_out + (size_t)rowF*HID + fg*4) =
                make_float4(z4[0],z4[1],z4[2],z4[3]);
          // final stage: no more barriers; blocks exit uniformly
        } else {
          __syncthreads();                       // zt(z) visible
          if (idx > 0) load_WT_split(WbT, p.w_gat, tid);  // restore w_gat^T hi/lo
          #pragma unroll
          for (int i=0;i<8;++i) yb8[i] = zt[rA*HID + off8 + i];  // new y state (fp32)
          if (seg == 0) pack_y(yt_bf, rA, off8, yb8);
          __syncthreads();
          h_stage(yt_bf, WbT, mt, nt, quad, lc, fg, rs, rowF, actF, h_wr, er_l, ar4);
          grid_bar(bar_b, NBLK_B * step); ++step;
          rd ^= 1;
        }
      }
    }
  }
}

// out = tanh(ret @ w_o1 + b_o1) @ w_o2 + b_o2, fp32 output
__global__ void __launch_bounds__(256, 2) out_kernel(
    const float* __restrict__ y_base,
    const float* __restrict__ w_o1, const float* __restrict__ b_o1,
    const float* __restrict__ w_o2, const float* __restrict__ b_o2,
    float* __restrict__ out)
{
  __shared__ float Wl[HID*HID];
  __shared__ float yt[ORPB*HID];
  const int tid = threadIdx.x;
  const int row0 = blockIdx.x * ORPB;
  const int rA = tid >> 4, tA = tid & 15;
  const int rowA = row0 + rA;
  {
    float4 v0 = *reinterpret_cast<const float4*>(y_base + rowA*HID + tA*8);
    float4 v1 = *reinterpret_cast<const float4*>(y_base + rowA*HID + tA*8 + 4);
    *reinterpret_cast<float4*>(yt + rA*HID + tA*8)     = v0;
    *reinterpret_cast<float4*>(yt + rA*HID + tA*8 + 4) = v1;
  }
  load_W<256>(Wl, w_o1, tid);
  __syncthreads();
  const int fg = tid & 31, rs = tid >> 5;
  float t0[4], t1[4];
  gemm128<8>(Wl, yt, fg, rs, t0, t1);
  #pragma unroll
  for (int i=0;i<4;++i){
    float bb = b_o1[fg*4+i];
    t0[i] = tanhf(t0[i] + bb);
    t1[i] = tanhf(t1[i] + bb);
  }
  __syncthreads();
  *reinterpret_cast<float4*>(yt + rs*HID + fg*4)     = make_float4(t0[0],t0[1],t0[2],t0[3]);
  *reinterpret_cast<float4*>(yt + (rs+8)*HID + fg*4) = make_float4(t1[0],t1[1],t1[2],t1[3]);
  load_W<256>(Wl, w_o2, tid);
  __syncthreads();
  float o0[4], o1[4];
  gemm128<8>(Wl, yt, fg, rs, o0, o1);
  const int rowF0 = row0 + rs, rowF1 = row0 + rs + 8;
  *reinterpret_cast<float4*>(out + rowF0*HID + fg*4) =
      make_float4(o0[0]+b_o2[fg*4+0], o0[1]+b_o2[fg*4+1], o0[2]+b_o2[fg*4+2], o0[3]+b_o2[fg*4+3]);
  *reinterpret_cast<float4*>(out + rowF1*HID + fg*4) =
      make_float4(o1[0]+b_o2[fg*4+0], o1[1]+b_o2[fg*4+1], o1[2]+b_o2[fg*4+2], o1[3]+b_o2[fg*4+3]);
}

extern "C" void kernel_launch(void* const* d_in, const int* in_sizes, int n_in,
                              void* d_out, int out_size, void* d_ws, size_t ws_size,
                              hipStream_t stream)
{
  const float* inputs = (const float*)d_in[0];
  const int* src      = (const int*)d_in[1];
  const int* dst      = (const int*)d_in[2];
  const float* w_in   = (const float*)d_in[3];
  const float* b_in   = (const float*)d_in[4];
  const float* w_gat  = (const float*)d_in[5];
  const float* a_l    = (const float*)d_in[6];
  const float* a_r    = (const float*)d_in[7];
  const float* w_W    = (const float*)d_in[8];
  const float* b_W    = (const float*)d_in[9];
  const float* w_U    = (const float*)d_in[10];
  const float* b_U    = (const float*)d_in[11];
  const float* w_o1   = (const float*)d_in[12];
  const float* b_o1   = (const float*)d_in[13];
  const float* w_o2   = (const float*)d_in[14];
  const float* b_o2   = (const float*)d_in[15];

  const size_t RH = (size_t)NROWS * HID;    // 1,024,000
  float* y_out = reinterpret_cast<float*>(d_ws);            // RH floats
  u16*   hbuf  = reinterpret_cast<u16*>(y_out + RH);        // 2*RH bf16
  u16*   hb0   = hbuf;
  u16*   hb1   = hbuf + RH;
  int*   I     = reinterpret_cast<int*>(hbuf + 2*RH);
  int* row_start = I;
  int* edge_src  = I + 1024;
  int* bar       = I + 1024 + NEDGE;

  size_t need = RH*sizeof(float) + 2*RH*sizeof(u16)
              + (size_t)(1024 + NEDGE + NBATCH*BARSTRIDE)*sizeof(int);
  if (ws_size < need) return;

  csr_kernel<<<1, 1024, 0, stream>>>(src, dst, row_start, edge_src, bar);

  PArgs pa;
  pa.hb0 = hb0; pa.hb1 = hb1; pa.y_out = y_out;
  pa.row_start = row_start; pa.edge_src = edge_src;
  pa.w_gat = w_gat; pa.a_l = a_l; pa.a_r = a_r;
  pa.inputs = inputs; pa.w_in = w_in; pa.b_in = b_in;
  pa.w_W = w_W; pa.b_W = b_W; pa.w_U = w_U; pa.b_U = b_U;
  pa.bar = bar;

  persist<<<NBLK_P, PTHREADS, 0, stream>>>(pa);

  out_kernel<<<NBLK_O, 256, 0, stream>>>(y_out, w_o1, b_o1, w_o2, b_o2, (float*)d_out);
}